// Round 2
// baseline (3351.580 us; speedup 1.0000x reference)
//
#include <hip/hip_runtime.h>
#include <math.h>

#define DIVUP(a,b) (((a)+(b)-1)/(b))

// ---------------------------------------------------------------------------
// Implicit-GEMM conv. POOL=0: writes raw [z][n][co][Hout][Wout].
// POOL=1: quad-ordered M (4 consecutive m = one 2x2 pool quad), writes pooled
// raw max [z][n][co][H2][W2]; raw pixels past floor-pool edge are computed
// (for stats) but not written.
// Both variants emit per-block per-channel (sum,sumsq) partials for BN stats.
// Optional fused BN+ReLU on the *input* (stats per (z,ci)).
// BM=BN=64, BK=16, 256 threads, 4x4 micro-tile.
// ---------------------------------------------------------------------------
template<int POOL>
__global__ __launch_bounds__(256) void conv_gemm(
    const float* __restrict__ in, long inPstride,
    const float2* __restrict__ bnstats, int use_bn,
    const float* __restrict__ wt, float* __restrict__ out,
    float2* __restrict__ part,
    int Bn, int Cin, int Hin, int Win, int Hout, int Wout,
    int Cout, int KH, int KW, int pad, int M, int K, int Kpad,
    int H2, int W2, int H2c, int W2c)
{
    __shared__ float  As[16][64];
    __shared__ float  Bs[16][64];
    __shared__ int4   ktab[576];
    __shared__ float2 red[64][16];

    const int tid    = threadIdx.x;
    const int HinWin = Hin * Win;
    const int KHKW   = KH * KW;

    for (int k = tid; k < Kpad; k += 256) {
        int4 e;
        if (k < K) {
            int ci = k / KHKW;
            int r  = k - ci * KHKW;
            int kh = r / KW;
            int kw = r - kh * KW;
            e.x = ci * HinWin + kh * Win + kw;
            e.y = (kh << 16) | kw;
            e.z = ci;
        } else { e.x = 0; e.y = (0x7FFF << 16) | 0x7FFF; e.z = 0; }
        e.w = 0;
        ktab[k] = e;
    }

    const int mload = tid & 63;
    const int kslot = tid >> 6;
    const int mA    = blockIdx.x * 64 + mload;
    int nb = 0, h = 0, w = 0;
    bool mvalid;
    if (POOL) {
        int r = mA & 3, quad = mA >> 2;
        int cpi = H2c * W2c;
        int nbq = quad / cpi;
        int rem = quad - nbq * cpi;
        int h2 = rem / W2c, w2 = rem - h2 * W2c;
        nb = nbq; h = h2 * 2 + (r >> 1); w = w2 * 2 + (r & 1);
        mvalid = (mA < M) && (h < Hout) && (w < Wout);
    } else {
        int HW = Hout * Wout;
        mvalid = mA < M;
        int mm = mvalid ? mA : 0;
        nb = mm / HW;
        int rem = mm - nb * HW;
        h = rem / Wout; w = rem - h * Wout;
    }
    if (!mvalid) { nb = 0; h = 0; w = 0; }
    const int h0 = h - pad, w0 = w - pad;

    const float*  inp    = in + (size_t)blockIdx.z * inPstride;
    const int     base_m = nb * Cin * HinWin + h0 * Win + w0;
    const float*  wtp    = wt + (size_t)blockIdx.z * Kpad * 64 + mload;
    const float2* bnp    = bnstats + (size_t)blockIdx.z * Cin;

    float acc[4][4] = {};
    float ar[4], brw[4];
    const int niter = Kpad / 16;
    const int tm = (tid & 15) * 4;
    const int tn = (tid >> 4) * 4;

    __syncthreads();  // ktab ready

    auto loadAB = [&](int it) {
        int kbase = it * 16 + kslot * 4;
#pragma unroll
        for (int j = 0; j < 4; ++j) {
            int4 e  = ktab[kbase + j];
            int  kh = e.y >> 16, kw = e.y & 0xFFFF;
            bool v  = mvalid && ((unsigned)(h0 + kh) < (unsigned)Hin)
                             && ((unsigned)(w0 + kw) < (unsigned)Win);
            float val = 0.f;
            if (v) {
                val = inp[base_m + e.x];
                if (use_bn) {
                    float2 s = bnp[e.z];
                    val = fmaxf((val - s.x) * s.y, 0.f);
                }
            }
            ar[j]  = val;
            brw[j] = wtp[(size_t)(kbase + j) * 64];
        }
    };

    loadAB(0);
    for (int it = 0; it < niter; ++it) {
        __syncthreads();
#pragma unroll
        for (int j = 0; j < 4; ++j) {
            As[kslot * 4 + j][mload] = ar[j];
            Bs[kslot * 4 + j][mload] = brw[j];
        }
        __syncthreads();
        if (it + 1 < niter) loadAB(it + 1);
#pragma unroll
        for (int kk = 0; kk < 16; ++kk) {
            float4 a4 = *(const float4*)&As[kk][tm];
            float4 b4 = *(const float4*)&Bs[kk][tn];
            float av[4] = {a4.x, a4.y, a4.z, a4.w};
            float bv[4] = {b4.x, b4.y, b4.z, b4.w};
#pragma unroll
            for (int i = 0; i < 4; ++i)
#pragma unroll
                for (int j = 0; j < 4; ++j)
                    acc[i][j] = fmaf(av[i], bv[j], acc[i][j]);
        }
    }

    // ---- per-block per-channel stats partials (invalid rows hold exact 0) ----
#pragma unroll
    for (int j = 0; j < 4; ++j) {
        float s = 0.f, s2 = 0.f;
#pragma unroll
        for (int i = 0; i < 4; ++i) { float v = acc[i][j]; s += v; s2 += v * v; }
        red[tn + j][tid & 15] = make_float2(s, s2);
    }
    __syncthreads();
    if (tid < 64) {
        float s = 0.f, s2 = 0.f;
#pragma unroll
        for (int q = 0; q < 16; ++q) { float2 v = red[tid][q]; s += v.x; s2 += v.y; }
        part[(size_t)(blockIdx.z * 64 + tid) * gridDim.x + blockIdx.x] = make_float2(s, s2);
    }

    // ---- output ----
    if (POOL) {
        int mA0 = blockIdx.x * 64 + tm;          // tm%4==0 -> rows i=0..3 are one quad
        if (mA0 < M) {
            int quad = mA0 >> 2;
            int cpi  = H2c * W2c;
            int nb2  = quad / cpi;
            int rem  = quad - nb2 * cpi;
            int h2 = rem / W2c, w2 = rem - h2 * W2c;
            if (h2 < H2 && w2 < W2) {            // full 2x2 quad guaranteed valid
                float* op = out + ((size_t)(blockIdx.z * Bn + nb2) * Cout) * (H2 * W2)
                                + h2 * W2 + w2;
#pragma unroll
                for (int j = 0; j < 4; ++j) {
                    int n = tn + j;
                    if (n < Cout) {
                        float mx = fmaxf(fmaxf(acc[0][j], acc[1][j]),
                                         fmaxf(acc[2][j], acc[3][j]));
                        op[(size_t)n * (H2 * W2)] = mx;
                    }
                }
            }
        }
    } else {
        int HW = Hout * Wout;
#pragma unroll
        for (int i = 0; i < 4; ++i) {
            int m = blockIdx.x * 64 + tm + i;
            if (m < M) {
                int nb2 = m / HW;
                int hw2 = m - nb2 * HW;
                float* op = out + ((size_t)(blockIdx.z * Bn + nb2) * Cout) * HW + hw2;
#pragma unroll
                for (int j = 0; j < 4; ++j) {
                    int n = tn + j;
                    if (n < Cout) op[(size_t)n * HW] = acc[i][j];
                }
            }
        }
    }
}

// partials -> (mean, rsqrt(var+eps)) per (z,channel); one block per channel
__global__ __launch_bounds__(256) void bn_finalize(const float2* __restrict__ part,
                                                   int nblkx, double Ninv,
                                                   float2* __restrict__ stats)
{
    __shared__ double sh[512];
    const int zc = blockIdx.x, tid = threadIdx.x;
    const float2* p = part + (size_t)zc * nblkx;
    double s = 0, s2 = 0;
    for (int i = tid; i < nblkx; i += 256) { s += p[i].x; s2 += p[i].y; }
    sh[tid] = s; sh[256 + tid] = s2;
    __syncthreads();
    for (int st = 128; st > 0; st >>= 1) {
        if (tid < st) { sh[tid] += sh[tid + st]; sh[256 + tid] += sh[256 + tid + st]; }
        __syncthreads();
    }
    if (tid == 0) {
        float mean = (float)(sh[0] * Ninv);
        float var  = (float)(sh[256] * Ninv - (double)mean * (double)mean);
        if (var < 0.f) var = 0.f;
        stats[zc] = make_float2(mean, rsqrtf(var + 1e-5f));
    }
}

// out[c][n][co][hw] = sum_p d[c,p] * relu((pooledraw[p][n][co][hw]-mean)*rs)
__global__ void mix_k(const float* __restrict__ pooled, const float2* __restrict__ stats,
                      const float* __restrict__ d, float* __restrict__ out,
                      int Bn, int Cout, int HW, int P)
{
    const int c   = blockIdx.z;
    const int bc  = blockIdx.y;          // n*Cout + co
    const int idx = blockIdx.x * 256 + threadIdx.x;
    if (idx >= HW) return;
    const int co = bc % Cout;
    const size_t strideP = (size_t)Bn * Cout * HW;
    const float* pp = pooled + (size_t)bc * HW + idx;
    float acc = 0.f;
    for (int p = 0; p < P; ++p) {
        float2 st = stats[p * 64 + co];
        float  v  = fmaxf((pp[p * strideP] - st.x) * st.y, 0.f);
        acc = fmaf(d[c * P + p], v, acc);
    }
    out[(size_t)c * strideP + (size_t)bc * HW + idx] = acc;
}

// W[p][co][ci][kh][kw] -> Wt[p][k (padded to Kpad)][co (padded to 64)]
__global__ void wtrans(const float* __restrict__ w, float* __restrict__ wt,
                       int P, int Cout, int Cin, int KHKW, int K, int Kpad)
{
    const int total = P * Kpad * 64;
    for (int i = blockIdx.x * 256 + threadIdx.x; i < total; i += gridDim.x * 256) {
        int n = i & 63;
        int k = (i >> 6) % Kpad;
        int p = (i >> 6) / Kpad;
        float v = 0.f;
        if (n < Cout && k < K) {
            int ci = k / KHKW;
            int r  = k - ci * KHKW;
            v = w[((size_t)(p * Cout + n) * Cin + ci) * KHKW + r];
        }
        wt[i] = v;
    }
}

// d = softmax_p( log(softmax_p(br*2)) / t ) for all 4 layers
__global__ void dcalc(const float* __restrict__ br0, const float* __restrict__ br1,
                      const float* __restrict__ br2, const float* __restrict__ br3,
                      const void* __restrict__ tptr, float* __restrict__ D)
{
    const int L = blockIdx.x;
    const float* br; int C, P, off;
    if      (L == 0) { br = br0; C = 4;  P = 2;  off = 0;   }
    else if (L == 1) { br = br1; C = 8;  P = 4;  off = 8;   }
    else if (L == 2) { br = br2; C = 16; P = 8;  off = 40;  }
    else             { br = br3; C = 40; P = 16; off = 168; }
    int ti = *(const int*)tptr;
    float t = (ti > 0 && ti < 1000000) ? (float)ti : *(const float*)tptr;
    const int c = threadIdx.x;
    if (c >= C) return;
    float u[16];
    float mx = -1e30f;
#pragma unroll
    for (int p = 0; p < 16; ++p) if (p < P) { u[p] = br[c * P + p] * 2.0f; mx = fmaxf(mx, u[p]); }
    float se = 0.f;
#pragma unroll
    for (int p = 0; p < 16; ++p) if (p < P) se += expf(u[p] - mx);
    float lse = mx + logf(se);
    float mx2 = -1e30f;
#pragma unroll
    for (int p = 0; p < 16; ++p) if (p < P) { u[p] = (u[p] - lse) / t; mx2 = fmaxf(mx2, u[p]); }
    float se2 = 0.f;
#pragma unroll
    for (int p = 0; p < 16; ++p) if (p < P) { u[p] = expf(u[p] - mx2); se2 += u[p]; }
#pragma unroll
    for (int p = 0; p < 16; ++p) if (p < P) D[off + c * P + p] = u[p] / se2;
}

// h1[a,b,i] = relu( sum_f f[a,b,f]*fw1[a,f,i] + fb1[a,i] )
__global__ __launch_bounds__(128) void fc1_k(const float* __restrict__ f,
                                             const float* __restrict__ w1,
                                             const float* __restrict__ b1,
                                             float* __restrict__ h1)
{
    const int a = blockIdx.x >> 4;
    const int b = blockIdx.x & 15;
    const int i = threadIdx.x;
    const float* fv = f + ((size_t)a * 16 + b) * 1568;
    const float* wv = w1 + (size_t)a * 1568 * 128 + i;
    float acc = b1[a * 128 + i];
    for (int ff = 0; ff < 1568; ++ff)
        acc = fmaf(fv[ff], wv[(size_t)ff * 128], acc);
    h1[((size_t)a * 16 + b) * 128 + i] = fmaxf(acc, 0.f);
}

// h2 = relu(h1 @ fw2 + fb2); o = h2 @ fw3 + fb3; out[b,a] = o[a,b]
__global__ __launch_bounds__(128) void fc23_k(const float* __restrict__ h1,
                                              const float* __restrict__ w2,
                                              const float* __restrict__ b2,
                                              const float* __restrict__ w3,
                                              const float* __restrict__ b3,
                                              float* __restrict__ out)
{
    __shared__ float sh1[16][128];
    __shared__ float sh2[16][128];
    const int a = blockIdx.x;
    const int i = threadIdx.x;
    for (int b = 0; b < 16; ++b) sh1[b][i] = h1[((size_t)a * 16 + b) * 128 + i];
    __syncthreads();
    float acc[16];
#pragma unroll
    for (int b = 0; b < 16; ++b) acc[b] = b2[a * 128 + i];
    for (int ff = 0; ff < 128; ++ff) {
        float wv = w2[((size_t)a * 128 + ff) * 128 + i];
#pragma unroll
        for (int b = 0; b < 16; ++b) acc[b] = fmaf(sh1[b][ff], wv, acc[b]);
    }
    for (int b = 0; b < 16; ++b) sh2[b][i] = fmaxf(acc[b], 0.f);
    __syncthreads();
    if (i < 16) {
        float o = b3[a];
        for (int ff = 0; ff < 128; ++ff) o = fmaf(sh2[i][ff], w3[a * 128 + ff], o);
        out[i * 40 + a] = o;
    }
}

extern "C" void kernel_launch(void* const* d_in, const int* in_sizes, int n_in,
                              void* d_out, int out_size, void* d_ws, size_t ws_size,
                              hipStream_t stream)
{
    (void)in_sizes; (void)n_in;

    const float* x   = (const float*)d_in[0];
    const float* w10 = (const float*)d_in[1];
    const float* wa[4] = {(const float*)d_in[3],  (const float*)d_in[7],
                          (const float*)d_in[11], (const float*)d_in[15]};
    const float* wb[4] = {(const float*)d_in[5],  (const float*)d_in[9],
                          (const float*)d_in[13], (const float*)d_in[17]};
    const float* br[4] = {(const float*)d_in[19], (const float*)d_in[20],
                          (const float*)d_in[21], (const float*)d_in[22]};
    const float* fw1 = (const float*)d_in[23];
    const float* fb1 = (const float*)d_in[24];
    const float* fw2 = (const float*)d_in[25];
    const float* fb2 = (const float*)d_in[26];
    const float* fw3 = (const float*)d_in[27];
    const float* fb3 = (const float*)d_in[28];
    float* out = (float*)d_out;

    const int Pl[4]  = {2, 4, 8, 16};
    const int Cs[4]  = {4, 8, 16, 40};
    const int CBs[4] = {64, 64, 64, 32};

    // ---- workspace layout (floats); guard against insufficient ws_size ----
    const size_t NEED = 60309376ull * 4ull;   // ~241.2 MB
    if (ws_size < NEED) {
        hipMemsetAsync(d_out, 0, (size_t)out_size * sizeof(float), stream);
        return;  // diagnosable: absmax failure instead of a crash
    }
    float* ws = (float*)d_ws;
    size_t o = 0;
    float* WT1 = ws + o; o += 160 * 64;
    float* WTA[4]; float* WTB[4];
    for (int L = 0; L < 4; ++L) {
        WTA[L] = ws + o; o += (size_t)Pl[L] * 576 * 64;
        WTB[L] = ws + o; o += (size_t)Pl[L] * 576 * 64;
    }
    float*  D        = ws + o; o += 1024;
    float2* STATS    = (float2*)(ws + o); o += 4352;     // 2176 float2
    float2* STATS_C1 = STATS;
    float2* STATS_A  = STATS + 64;
    float2* STATS_B  = STATS + 1088;
    float2* PARTF    = (float2*)(ws + o); o += 2000000;  // 1M float2
    float*  H1       = ws + o; o += 81920;
    float*  B0 = ws + o; o += 16000000;
    float*  B1 = ws + o; o += 16000000;
    float*  B2 = ws + o; o += 16000000;
    float*  B3 = ws + o; o += 8000000;

    // ---- weight transposes + branch-mix coefficients ----
    wtrans<<<40, 256, 0, stream>>>(w10, WT1, 1, 64, 3, 49, 147, 160);
    for (int L = 0; L < 4; ++L) {
        int tA = Pl[L] * 576 * 64;
        wtrans<<<DIVUP(tA, 256), 256, 0, stream>>>(wa[L], WTA[L], Pl[L], 64,      64, 9, 576, 576);
        wtrans<<<DIVUP(tA, 256), 256, 0, stream>>>(wb[L], WTB[L], Pl[L], CBs[L],  64, 9, 576, 576);
    }
    dcalc<<<4, 64, 0, stream>>>(br[0], br[1], br[2], br[3], d_in[29], D);

    // ---- conv1 (7x7, pad0) fused pool+stats: x[16,3,256,256] -> Y=B0 [16,64,125,125]
    conv_gemm<1><<<dim3(15625, 1, 1), 256, 0, stream>>>(
        x, 0, nullptr, 0, WT1, B0, PARTF,
        16, 3, 256, 256, 250, 250, 64, 7, 7, 0,
        1000000, 147, 160, 125, 125, 125, 125);
    bn_finalize<<<64, 256, 0, stream>>>(PARTF, 15625, 1.0 / 1000000.0, STATS_C1);

    // ---- layer 0 (per parent): in Y(B0)+BN -> RA(B1) -> pooled(B3) -> mix -> XB0(B2)
    for (int p = 0; p < 2; ++p) {
        conv_gemm<0><<<dim3(3907, 1, 1), 256, 0, stream>>>(
            B0, 0, STATS_C1, 1, WTA[0] + (size_t)p * 36864, B1, PARTF,
            16, 64, 125, 125, 125, 125, 64, 3, 3, 1,
            250000, 576, 576, 0, 0, 1, 1);
        bn_finalize<<<64, 256, 0, stream>>>(PARTF, 3907, 1.0 / 250000.0, STATS_A);
        conv_gemm<1><<<dim3(3970, 1, 1), 256, 0, stream>>>(
            B1, 0, STATS_A, 1, WTB[0] + (size_t)p * 36864, B3 + (size_t)p * 3936256, PARTF,
            16, 64, 125, 125, 125, 125, 64, 3, 3, 1,
            254016, 576, 576, 62, 62, 63, 63);
        bn_finalize<<<64, 256, 0, stream>>>(PARTF, 3970, 1.0 / 250000.0, STATS_B + (size_t)p * 64);
    }
    mix_k<<<dim3(16, 1024, 4), 256, 0, stream>>>(B3, STATS_B, D + 0, B2, 16, 64, 3844, 2);

    // ---- layer 1: XB0(B2) -> RA(B1) -> pooled(B3) -> mix -> XB1(B0)
    conv_gemm<0><<<dim3(961, 1, 4), 256, 0, stream>>>(
        B2, (long)16 * 64 * 3844, nullptr, 0, WTA[1], B1, PARTF,
        16, 64, 62, 62, 62, 62, 64, 3, 3, 1, 61504, 576, 576, 0, 0, 1, 1);
    bn_finalize<<<256, 256, 0, stream>>>(PARTF, 961, 1.0 / 61504.0, STATS_A);
    conv_gemm<1><<<dim3(961, 1, 4), 256, 0, stream>>>(
        B1, (long)16 * 64 * 3844, STATS_A, 1, WTB[1], B3, PARTF,
        16, 64, 62, 62, 62, 62, 64, 3, 3, 1, 61504, 576, 576, 31, 31, 31, 31);
    bn_finalize<<<256, 256, 0, stream>>>(PARTF, 961, 1.0 / 61504.0, STATS_B);
    mix_k<<<dim3(4, 1024, 8), 256, 0, stream>>>(B3, STATS_B, D + 8, B0, 16, 64, 961, 4);

    // ---- layer 2: XB1(B0) -> RA(B1) -> pooled(B3) -> mix -> XB2(B2)
    conv_gemm<0><<<dim3(241, 1, 8), 256, 0, stream>>>(
        B0, (long)16 * 64 * 961, nullptr, 0, WTA[2], B1, PARTF,
        16, 64, 31, 31, 31, 31, 64, 3, 3, 1, 15376, 576, 576, 0, 0, 1, 1);
    bn_finalize<<<512, 256, 0, stream>>>(PARTF, 241, 1.0 / 15376.0, STATS_A);
    conv_gemm<1><<<dim3(256, 1, 8), 256, 0, stream>>>(
        B1, (long)16 * 64 * 961, STATS_A, 1, WTB[2], B3, PARTF,
        16, 64, 31, 31, 31, 31, 64, 3, 3, 1, 16384, 576, 576, 15, 15, 16, 16);
    bn_finalize<<<512, 256, 0, stream>>>(PARTF, 256, 1.0 / 15376.0, STATS_B);
    mix_k<<<dim3(1, 1024, 16), 256, 0, stream>>>(B3, STATS_B, D + 40, B2, 16, 64, 225, 8);

    // ---- layer 3: XB2(B2) -> RA(B1) -> pooled(B3) -> mix -> XB3(B0)
    conv_gemm<0><<<dim3(57, 1, 16), 256, 0, stream>>>(
        B2, (long)16 * 64 * 225, nullptr, 0, WTA[3], B1, PARTF,
        16, 64, 15, 15, 15, 15, 64, 3, 3, 1, 3600, 576, 576, 0, 0, 1, 1);
    bn_finalize<<<1024, 256, 0, stream>>>(PARTF, 57, 1.0 / 3600.0, STATS_A);
    conv_gemm<1><<<dim3(64, 1, 16), 256, 0, stream>>>(
        B1, (long)16 * 64 * 225, STATS_A, 1, WTB[3], B3, PARTF,
        16, 64, 15, 15, 15, 15, 32, 3, 3, 1, 4096, 576, 576, 7, 7, 8, 8);
    bn_finalize<<<1024, 256, 0, stream>>>(PARTF, 64, 1.0 / 3600.0, STATS_B);
    mix_k<<<dim3(1, 512, 40), 256, 0, stream>>>(B3, STATS_B, D + 168, B0, 16, 32, 49, 16);

    // ---- FC heads: f = XB3(B0) [40,16,1568] ----
    fc1_k<<<640, 128, 0, stream>>>(B0, fw1, fb1, H1);
    fc23_k<<<40, 128, 0, stream>>>(H1, fw2, fb2, fw3, fb3, out);
}

// Round 4
// 2439.578 us; speedup vs baseline: 1.3738x; 1.3738x over previous
//
#include <hip/hip_runtime.h>
#include <math.h>

#define DIVUP(a,b) (((a)+(b)-1)/(b))

typedef __bf16 bf16x8 __attribute__((ext_vector_type(8)));
typedef float  f32x4  __attribute__((ext_vector_type(4)));

// ---------------------------------------------------------------------------
// Implicit-GEMM conv via split-bf16 MFMA (fp32 accumulate, ~fp32 accuracy):
// A = aH + aL, W = bH + bL (bf16 hi/lo split); acc += aH*bH + aL*bH + aH*bL.
// POOL=0: raw [z][n][co][Hout][Wout]; POOL=1: quad-ordered M, fused 2x2 maxpool.
// Per-block per-channel (sum,sumsq) partials for BN. Optional BN+ReLU on input.
// BM=64, BN=64 (co padded), BK=32. 256 threads = 4 waves; wave w owns rows
// 16w..16w+15. Frags (16x16x32): A row=lane&15, k=(lane>>4)*8+j; C/D
// col=lane&15, row=(lane>>4)*4+reg  [HW-verified m89].
// ---------------------------------------------------------------------------
template<int POOL>
__global__ __launch_bounds__(256) void conv_mfma(
    const float* __restrict__ in, long inPstride,
    const float2* __restrict__ bnstats, int use_bn,
    const __bf16* __restrict__ wt_hi, const __bf16* __restrict__ wt_lo,
    float* __restrict__ out, float2* __restrict__ part,
    int Bn, int Cin, int Hin, int Win, int Hout, int Wout,
    int Cout, int KH, int KW, int pad, int M, int K, int Kpad,
    int H2, int W2, int H2c, int W2c)
{
    __shared__ __align__(16) char smem[20480 + 9216];
    __bf16* AsH  = (__bf16*)smem;             // [64][40] bf16 (pad->conflict-free)
    __bf16* AsL  = (__bf16*)(smem + 5120);
    __bf16* BsH  = (__bf16*)(smem + 10240);
    __bf16* BsL  = (__bf16*)(smem + 15360);
    int4*   ktab = (int4*)(smem + 20480);     // [<=576]
    float2* red  = (float2*)smem;             // [64][16], reused after K loop

    const int tid    = threadIdx.x;
    const int HinWin = Hin * Win;
    const int KHKW   = KH * KW;

    for (int k = tid; k < Kpad; k += 256) {
        int4 e;
        if (k < K) {
            int ci = k / KHKW;
            int r  = k - ci * KHKW;
            int kh = r / KW;
            int kw = r - kh * KW;
            e.x = ci * HinWin + kh * Win + kw;
            e.y = (kh << 16) | kw;
            e.z = ci;
        } else { e.x = 0; e.y = (0x7FFF << 16) | 0x7FFF; e.z = 0; }
        e.w = 0;
        ktab[k] = e;
    }

    // ---- staging-thread geometry: this thread stages m = blk*64 + (tid&63) ----
    const int mload = tid & 63;
    const int wv    = tid >> 6;
    const int mA    = blockIdx.x * 64 + mload;
    int nb = 0, h = 0, w = 0;
    bool mvalid;
    if (POOL) {
        int r = mA & 3, quad = mA >> 2;
        int cpi = H2c * W2c;
        int nbq = quad / cpi;
        int rem = quad - nbq * cpi;
        int h2 = rem / W2c, w2 = rem - h2 * W2c;
        nb = nbq; h = h2 * 2 + (r >> 1); w = w2 * 2 + (r & 1);
        mvalid = (mA < M) && (h < Hout) && (w < Wout);
    } else {
        int HW = Hout * Wout;
        mvalid = mA < M;
        int mm = mvalid ? mA : 0;
        nb = mm / HW;
        int rem = mm - nb * HW;
        h = rem / Wout; w = rem - h * Wout;
    }
    if (!mvalid) { nb = 0; h = 0; w = 0; }
    const int h0 = h - pad, w0 = w - pad;

    const float*  inp    = in + (size_t)blockIdx.z * inPstride;
    const int     base_m = nb * Cin * HinWin + h0 * Win + w0;
    const size_t  woff   = (size_t)blockIdx.z * (Kpad >> 3) * 512;
    const __bf16* wtpH   = wt_hi + woff;
    const __bf16* wtpL   = wt_lo + woff;
    const float2* bnp    = bnstats + (size_t)blockIdx.z * Cin;

    f32x4 acc[4] = {};
    bf16x8 arH, arL, brH, brL;
    const int niter = Kpad / 32;

    const int ln15 = tid & 15;
    const int lhi  = (tid >> 4) & 3;

    __syncthreads();  // ktab ready

    auto loadA = [&](int it) {
        int kb = it * 32 + wv * 8;
#pragma unroll
        for (int j = 0; j < 8; ++j) {
            int4 e  = ktab[kb + j];
            int  kh = e.y >> 16, kw = e.y & 0xFFFF;
            bool v  = mvalid && ((unsigned)(h0 + kh) < (unsigned)Hin)
                             && ((unsigned)(w0 + kw) < (unsigned)Win);
            float val = 0.f;
            if (v) {
                val = inp[base_m + e.x];
                if (use_bn) {
                    float2 s = bnp[e.z];
                    val = fmaxf((val - s.x) * s.y, 0.f);
                }
            }
            __bf16 hi = (__bf16)val;
            arH[j] = hi;
            arL[j] = (__bf16)(val - (float)hi);
        }
    };
    auto loadB = [&](int it) {
        size_t idx = (size_t)((it * 4 + wv) * 64 + mload) << 3;
        brH = *(const bf16x8*)(wtpH + idx);
        brL = *(const bf16x8*)(wtpL + idx);
    };

    loadA(0); loadB(0);
    for (int it = 0; it < niter; ++it) {
        __syncthreads();
        *(bf16x8*)&AsH[mload * 40 + wv * 8] = arH;
        *(bf16x8*)&AsL[mload * 40 + wv * 8] = arL;
        *(bf16x8*)&BsH[mload * 40 + wv * 8] = brH;
        *(bf16x8*)&BsL[mload * 40 + wv * 8] = brL;
        __syncthreads();
        if (it + 1 < niter) { loadA(it + 1); loadB(it + 1); }

        bf16x8 afH = *(const bf16x8*)&AsH[(wv * 16 + ln15) * 40 + lhi * 8];
        bf16x8 afL = *(const bf16x8*)&AsL[(wv * 16 + ln15) * 40 + lhi * 8];
#pragma unroll
        for (int t = 0; t < 4; ++t) {
            bf16x8 bH = *(const bf16x8*)&BsH[(t * 16 + ln15) * 40 + lhi * 8];
            bf16x8 bL = *(const bf16x8*)&BsL[(t * 16 + ln15) * 40 + lhi * 8];
            acc[t] = __builtin_amdgcn_mfma_f32_16x16x32_bf16(afH, bH, acc[t], 0, 0, 0);
            acc[t] = __builtin_amdgcn_mfma_f32_16x16x32_bf16(afL, bH, acc[t], 0, 0, 0);
            acc[t] = __builtin_amdgcn_mfma_f32_16x16x32_bf16(afH, bL, acc[t], 0, 0, 0);
        }
    }

    // ---- per-block per-channel stats partials (invalid rows are exact 0) ----
    __syncthreads();  // done reading tiles; reuse as red[]
#pragma unroll
    for (int t = 0; t < 4; ++t) {
        float s = 0.f, s2 = 0.f;
#pragma unroll
        for (int r = 0; r < 4; ++r) { float v = acc[t][r]; s += v; s2 += v * v; }
        red[(ln15 + 16 * t) * 16 + (wv * 4 + lhi)] = make_float2(s, s2);
    }
    __syncthreads();
    if (tid < 64) {
        float s = 0.f, s2 = 0.f;
#pragma unroll
        for (int q = 0; q < 16; ++q) { float2 v = red[tid * 16 + q]; s += v.x; s2 += v.y; }
        part[(size_t)(blockIdx.z * 64 + tid) * gridDim.x + blockIdx.x] = make_float2(s, s2);
    }

    // ---- output ----
    const int mbase = blockIdx.x * 64 + wv * 16 + lhi * 4;   // 4 consecutive m
    if (POOL) {
        if (mbase < M) {
            int quad = mbase >> 2;
            int cpi  = H2c * W2c;
            int nb2  = quad / cpi;
            int rem  = quad - nb2 * cpi;
            int h2 = rem / W2c, w2 = rem - h2 * W2c;
            if (h2 < H2 && w2 < W2) {
                float* op = out + ((size_t)(blockIdx.z * Bn + nb2) * Cout) * (H2 * W2)
                                + h2 * W2 + w2;
#pragma unroll
                for (int t = 0; t < 4; ++t) {
                    int n = ln15 + 16 * t;
                    if (n < Cout) {
                        float mx = fmaxf(fmaxf(acc[t][0], acc[t][1]),
                                         fmaxf(acc[t][2], acc[t][3]));
                        op[(size_t)n * (H2 * W2)] = mx;
                    }
                }
            }
        }
    } else {
        int HW = Hout * Wout;
#pragma unroll
        for (int r = 0; r < 4; ++r) {
            int m = mbase + r;
            if (m < M) {
                int nb2 = m / HW;
                int hw2 = m - nb2 * HW;
                float* op = out + ((size_t)(blockIdx.z * Bn + nb2) * Cout) * HW + hw2;
#pragma unroll
                for (int t = 0; t < 4; ++t) {
                    int n = ln15 + 16 * t;
                    if (n < Cout) op[(size_t)n * HW] = acc[t][r];
                }
            }
        }
    }
}

// partials -> (mean, rsqrt(var+eps)) per (z,channel)
__global__ __launch_bounds__(256) void bn_finalize(const float2* __restrict__ part,
                                                   int nblkx, double Ninv,
                                                   float2* __restrict__ stats)
{
    __shared__ double sh[512];
    const int zc = blockIdx.x, tid = threadIdx.x;
    const float2* p = part + (size_t)zc * nblkx;
    double s = 0, s2 = 0;
    for (int i = tid; i < nblkx; i += 256) { s += p[i].x; s2 += p[i].y; }
    sh[tid] = s; sh[256 + tid] = s2;
    __syncthreads();
    for (int st = 128; st > 0; st >>= 1) {
        if (tid < st) { sh[tid] += sh[tid + st]; sh[256 + tid] += sh[256 + tid + st]; }
        __syncthreads();
    }
    if (tid == 0) {
        float mean = (float)(sh[0] * Ninv);
        float var  = (float)(sh[256] * Ninv - (double)mean * (double)mean);
        if (var < 0.f) var = 0.f;
        stats[zc] = make_float2(mean, rsqrtf(var + 1e-5f));
    }
}

// out[c][n][co][hw] = sum_p d[c,p] * relu((pooledraw[p][n][co][hw]-mean)*rs)
__global__ void mix_k(const float* __restrict__ pooled, const float2* __restrict__ stats,
                      const float* __restrict__ d, float* __restrict__ out,
                      int Bn, int Cout, int HW, int P)
{
    const int c   = blockIdx.z;
    const int bc  = blockIdx.y;          // n*Cout + co
    const int idx = blockIdx.x * 256 + threadIdx.x;
    if (idx >= HW) return;
    const int co = bc % Cout;
    const size_t strideP = (size_t)Bn * Cout * HW;
    const float* pp = pooled + (size_t)bc * HW + idx;
    float acc = 0.f;
    for (int p = 0; p < P; ++p) {
        float2 st = stats[p * 64 + co];
        float  v  = fmaxf((pp[p * strideP] - st.x) * st.y, 0.f);
        acc = fmaf(d[c * P + p], v, acc);
    }
    out[(size_t)c * strideP + (size_t)bc * HW + idx] = acc;
}

// W[p][co][ci][kh][kw] fp32 -> bf16 hi/lo k-panels [p][kblk][n(64)][8], zero-pad
__global__ void wtrans(const float* __restrict__ w, __bf16* __restrict__ wt_hi,
                       __bf16* __restrict__ wt_lo,
                       int P, int Cout, int Cin, int KHKW, int K, int Kpad)
{
    const int kblks = Kpad >> 3;
    const int total = P * kblks * 512;
    for (int i = blockIdx.x * 256 + threadIdx.x; i < total; i += gridDim.x * 256) {
        int j  = i & 7;
        int n  = (i >> 3) & 63;
        int kb = (i >> 9) % kblks;
        int p  = i / (kblks << 9);
        int k  = kb * 8 + j;
        float v = 0.f;
        if (n < Cout && k < K) {
            int ci = k / KHKW;
            int r  = k - ci * KHKW;
            v = w[((size_t)(p * Cout + n) * Cin + ci) * KHKW + r];
        }
        __bf16 hi = (__bf16)v;
        wt_hi[i] = hi;
        wt_lo[i] = (__bf16)(v - (float)hi);
    }
}

// d = softmax_p( log(softmax_p(br*2)) / t ) for all 4 layers
__global__ void dcalc(const float* __restrict__ br0, const float* __restrict__ br1,
                      const float* __restrict__ br2, const float* __restrict__ br3,
                      const void* __restrict__ tptr, float* __restrict__ D)
{
    const int L = blockIdx.x;
    const float* br; int C, P, off;
    if      (L == 0) { br = br0; C = 4;  P = 2;  off = 0;   }
    else if (L == 1) { br = br1; C = 8;  P = 4;  off = 8;   }
    else if (L == 2) { br = br2; C = 16; P = 8;  off = 40;  }
    else             { br = br3; C = 40; P = 16; off = 168; }
    int ti = *(const int*)tptr;
    float t = (ti > 0 && ti < 1000000) ? (float)ti : *(const float*)tptr;
    const int c = threadIdx.x;
    if (c >= C) return;
    float u[16];
    float mx = -1e30f;
#pragma unroll
    for (int p = 0; p < 16; ++p) if (p < P) { u[p] = br[c * P + p] * 2.0f; mx = fmaxf(mx, u[p]); }
    float se = 0.f;
#pragma unroll
    for (int p = 0; p < 16; ++p) if (p < P) se += expf(u[p] - mx);
    float lse = mx + logf(se);
    float mx2 = -1e30f;
#pragma unroll
    for (int p = 0; p < 16; ++p) if (p < P) { u[p] = (u[p] - lse) / t; mx2 = fmaxf(mx2, u[p]); }
    float se2 = 0.f;
#pragma unroll
    for (int p = 0; p < 16; ++p) if (p < P) { u[p] = expf(u[p] - mx2); se2 += u[p]; }
#pragma unroll
    for (int p = 0; p < 16; ++p) if (p < P) D[off + c * P + p] = u[p] / se2;
}

// h1[a,b,i] = relu( sum_f f[a,b,f]*fw1[a,f,i] + fb1[a,i] )
__global__ __launch_bounds__(128) void fc1_k(const float* __restrict__ f,
                                             const float* __restrict__ w1,
                                             const float* __restrict__ b1,
                                             float* __restrict__ h1)
{
    const int a = blockIdx.x >> 4;
    const int b = blockIdx.x & 15;
    const int i = threadIdx.x;
    const float* fv = f + ((size_t)a * 16 + b) * 1568;
    const float* wv = w1 + (size_t)a * 1568 * 128 + i;
    float acc = b1[a * 128 + i];
    for (int ff = 0; ff < 1568; ++ff)
        acc = fmaf(fv[ff], wv[(size_t)ff * 128], acc);
    h1[((size_t)a * 16 + b) * 128 + i] = fmaxf(acc, 0.f);
}

// h2 = relu(h1 @ fw2 + fb2); o = h2 @ fw3 + fb3; out[b,a] = o[a,b]
__global__ __launch_bounds__(128) void fc23_k(const float* __restrict__ h1,
                                              const float* __restrict__ w2,
                                              const float* __restrict__ b2,
                                              const float* __restrict__ w3,
                                              const float* __restrict__ b3,
                                              float* __restrict__ out)
{
    __shared__ float sh1[16][128];
    __shared__ float sh2[16][128];
    const int a = blockIdx.x;
    const int i = threadIdx.x;
    for (int b = 0; b < 16; ++b) sh1[b][i] = h1[((size_t)a * 16 + b) * 128 + i];
    __syncthreads();
    float acc[16];
#pragma unroll
    for (int b = 0; b < 16; ++b) acc[b] = b2[a * 128 + i];
    for (int ff = 0; ff < 128; ++ff) {
        float wv = w2[((size_t)a * 128 + ff) * 128 + i];
#pragma unroll
        for (int b = 0; b < 16; ++b) acc[b] = fmaf(sh1[b][ff], wv, acc[b]);
    }
    for (int b = 0; b < 16; ++b) sh2[b][i] = fmaxf(acc[b], 0.f);
    __syncthreads();
    if (i < 16) {
        float o = b3[a];
        for (int ff = 0; ff < 128; ++ff) o = fmaf(sh2[i][ff], w3[a * 128 + ff], o);
        out[i * 40 + a] = o;
    }
}

extern "C" void kernel_launch(void* const* d_in, const int* in_sizes, int n_in,
                              void* d_out, int out_size, void* d_ws, size_t ws_size,
                              hipStream_t stream)
{
    (void)in_sizes; (void)n_in;

    const float* x   = (const float*)d_in[0];
    const float* w10 = (const float*)d_in[1];
    const float* wa[4] = {(const float*)d_in[3],  (const float*)d_in[7],
                          (const float*)d_in[11], (const float*)d_in[15]};
    const float* wb[4] = {(const float*)d_in[5],  (const float*)d_in[9],
                          (const float*)d_in[13], (const float*)d_in[17]};
    const float* br[4] = {(const float*)d_in[19], (const float*)d_in[20],
                          (const float*)d_in[21], (const float*)d_in[22]};
    const float* fw1 = (const float*)d_in[23];
    const float* fb1 = (const float*)d_in[24];
    const float* fw2 = (const float*)d_in[25];
    const float* fb2 = (const float*)d_in[26];
    const float* fw3 = (const float*)d_in[27];
    const float* fb3 = (const float*)d_in[28];
    float* out = (float*)d_out;

    const int Pl[4]  = {2, 4, 8, 16};
    const int CBs[4] = {64, 64, 64, 32};

    // ---- workspace layout (float units); guard against insufficient ws_size ----
    const size_t NEED = 58833664ull * 4ull;   // ~235.3 MB
    if (ws_size < NEED) {
        hipMemsetAsync(d_out, 0, (size_t)out_size * sizeof(float), stream);
        return;
    }
    float* ws = (float*)d_ws;
    size_t o = 0;
    __bf16* WT1H = (__bf16*)(ws + o); o += 5120;   // 20 kblk * 512 bf16 = 5120 f32
    __bf16* WT1L = (__bf16*)(ws + o); o += 5120;
    __bf16 *WTAH[4], *WTAL[4], *WTBH[4], *WTBL[4];
    for (int L = 0; L < 4; ++L) {                  // 72 kblk * 512 bf16 per parent
        WTAH[L] = (__bf16*)(ws + o); o += (size_t)Pl[L] * 18432;
        WTAL[L] = (__bf16*)(ws + o); o += (size_t)Pl[L] * 18432;
        WTBH[L] = (__bf16*)(ws + o); o += (size_t)Pl[L] * 18432;
        WTBL[L] = (__bf16*)(ws + o); o += (size_t)Pl[L] * 18432;
    }
    float*  D        = ws + o; o += 1024;
    float2* STATS    = (float2*)(ws + o); o += 4352;
    float2* STATS_C1 = STATS;
    float2* STATS_A  = STATS + 64;
    float2* STATS_B  = STATS + 1088;
    float2* PART     = (float2*)(ws + o); o += 524288;  // 262144 float2
    float*  H1       = ws + o; o += 81920;
    float*  B0 = ws + o; o += 16000000;
    float*  B1 = ws + o; o += 16000000;
    float*  B2 = ws + o; o += 16000000;
    float*  B3 = ws + o; o += 8000000;
    // conv1 needs 15625*64 partials -> overlay on B2 (B2 first written later)
    float2* PART_C1 = (float2*)B2;

    // ---- weight transposes (fp32 -> bf16 hi/lo k-panels) + mix coefficients ----
    wtrans<<<40, 256, 0, stream>>>(w10, WT1H, WT1L, 1, 64, 3, 49, 147, 160);
    for (int L = 0; L < 4; ++L) {
        int tA = Pl[L] * 72 * 512;
        wtrans<<<DIVUP(tA, 256), 256, 0, stream>>>(wa[L], WTAH[L], WTAL[L],
                                                   Pl[L], 64, 64, 9, 576, 576);
        wtrans<<<DIVUP(tA, 256), 256, 0, stream>>>(wb[L], WTBH[L], WTBL[L],
                                                   Pl[L], CBs[L], 64, 9, 576, 576);
    }
    dcalc<<<4, 64, 0, stream>>>(br[0], br[1], br[2], br[3], d_in[29], D);

    // ---- conv1 (7x7, pad0) fused pool+stats: x[16,3,256,256] -> Y=B0 [16,64,125,125]
    conv_mfma<1><<<dim3(15625, 1, 1), 256, 0, stream>>>(
        x, 0, nullptr, 0, WT1H, WT1L, B0, PART_C1,
        16, 3, 256, 256, 250, 250, 64, 7, 7, 0,
        1000000, 147, 160, 125, 125, 125, 125);
    bn_finalize<<<64, 256, 0, stream>>>(PART_C1, 15625, 1.0 / 1000000.0, STATS_C1);

    // ---- layer 0 (per parent): Y(B0)+BN -> raw(B1) -> pooled(B3) -> mix -> XB0(B2)
    for (int p = 0; p < 2; ++p) {
        conv_mfma<0><<<dim3(3907, 1, 1), 256, 0, stream>>>(
            B0, 0, STATS_C1, 1, WTAH[0] + (size_t)p * 36864, WTAL[0] + (size_t)p * 36864,
            B1, PART,
            16, 64, 125, 125, 125, 125, 64, 3, 3, 1,
            250000, 576, 576, 0, 0, 1, 1);
        bn_finalize<<<64, 256, 0, stream>>>(PART, 3907, 1.0 / 250000.0, STATS_A);
        conv_mfma<1><<<dim3(3969, 1, 1), 256, 0, stream>>>(
            B1, 0, STATS_A, 1, WTBH[0] + (size_t)p * 36864, WTBL[0] + (size_t)p * 36864,
            B3 + (size_t)p * 3936256, PART,
            16, 64, 125, 125, 125, 125, 64, 3, 3, 1,
            254016, 576, 576, 62, 62, 63, 63);
        bn_finalize<<<64, 256, 0, stream>>>(PART, 3969, 1.0 / 250000.0, STATS_B + (size_t)p * 64);
    }
    mix_k<<<dim3(16, 1024, 4), 256, 0, stream>>>(B3, STATS_B, D + 0, B2, 16, 64, 3844, 2);

    // ---- layer 1: XB0(B2) -> raw(B1) -> pooled(B3) -> mix -> XB1(B0)
    conv_mfma<0><<<dim3(961, 1, 4), 256, 0, stream>>>(
        B2, (long)16 * 64 * 3844, nullptr, 0, WTAH[1], WTAL[1], B1, PART,
        16, 64, 62, 62, 62, 62, 64, 3, 3, 1, 61504, 576, 576, 0, 0, 1, 1);
    bn_finalize<<<256, 256, 0, stream>>>(PART, 961, 1.0 / 61504.0, STATS_A);
    conv_mfma<1><<<dim3(961, 1, 4), 256, 0, stream>>>(
        B1, (long)16 * 64 * 3844, STATS_A, 1, WTBH[1], WTBL[1], B3, PART,
        16, 64, 62, 62, 62, 62, 64, 3, 3, 1, 61504, 576, 576, 31, 31, 31, 31);
    bn_finalize<<<256, 256, 0, stream>>>(PART, 961, 1.0 / 61504.0, STATS_B);
    mix_k<<<dim3(4, 1024, 8), 256, 0, stream>>>(B3, STATS_B, D + 8, B0, 16, 64, 961, 4);

    // ---- layer 2: XB1(B0) -> raw(B1) -> pooled(B3) -> mix -> XB2(B2)
    conv_mfma<0><<<dim3(241, 1, 8), 256, 0, stream>>>(
        B0, (long)16 * 64 * 961, nullptr, 0, WTAH[2], WTAL[2], B1, PART,
        16, 64, 31, 31, 31, 31, 64, 3, 3, 1, 15376, 576, 576, 0, 0, 1, 1);
    bn_finalize<<<512, 256, 0, stream>>>(PART, 241, 1.0 / 15376.0, STATS_A);
    conv_mfma<1><<<dim3(256, 1, 8), 256, 0, stream>>>(
        B1, (long)16 * 64 * 961, STATS_A, 1, WTBH[2], WTBL[2], B3, PART,
        16, 64, 31, 31, 31, 31, 64, 3, 3, 1, 16384, 576, 576, 15, 15, 16, 16);
    bn_finalize<<<512, 256, 0, stream>>>(PART, 256, 1.0 / 15376.0, STATS_B);
    mix_k<<<dim3(1, 1024, 16), 256, 0, stream>>>(B3, STATS_B, D + 40, B2, 16, 64, 225, 8);

    // ---- layer 3: XB2(B2) -> raw(B1) -> pooled(B3) -> mix -> XB3(B0)
    conv_mfma<0><<<dim3(57, 1, 16), 256, 0, stream>>>(
        B2, (long)16 * 64 * 225, nullptr, 0, WTAH[3], WTAL[3], B1, PART,
        16, 64, 15, 15, 15, 15, 64, 3, 3, 1, 3600, 576, 576, 0, 0, 1, 1);
    bn_finalize<<<1024, 256, 0, stream>>>(PART, 57, 1.0 / 3600.0, STATS_A);
    conv_mfma<1><<<dim3(64, 1, 16), 256, 0, stream>>>(
        B1, (long)16 * 64 * 225, STATS_A, 1, WTBH[3], WTBL[3], B3, PART,
        16, 64, 15, 15, 15, 15, 32, 3, 3, 1, 4096, 576, 576, 7, 7, 8, 8);
    bn_finalize<<<1024, 256, 0, stream>>>(PART, 64, 1.0 / 3600.0, STATS_B);
    mix_k<<<dim3(1, 512, 40), 256, 0, stream>>>(B3, STATS_B, D + 168, B0, 16, 32, 49, 16);

    // ---- FC heads: f = XB3(B0) [40,16,1568] ----
    fc1_k<<<640, 128, 0, stream>>>(B0, fw1, fb1, H1);
    fc23_k<<<40, 128, 0, stream>>>(H1, fw2, fb2, fw3, fb3, out);
}

// Round 5
// 1343.406 us; speedup vs baseline: 2.4948x; 1.8160x over previous
//
#include <hip/hip_runtime.h>
#include <math.h>

#define DIVUP(a,b) (((a)+(b)-1)/(b))

typedef __bf16 bf16x8 __attribute__((ext_vector_type(8)));
typedef __bf16 bf16x4 __attribute__((ext_vector_type(4)));
typedef float  f32x4  __attribute__((ext_vector_type(4)));

// ---------------------------------------------------------------------------
// Implicit-GEMM conv, NHWC, split-bf16 3-MFMA (fp32-grade accuracy).
// Inputs are pre-split bf16 hi/lo. C1=0: 3x3 pad=1 on a zero-bordered
// [*][HinP][WinP][64] buffer -> no bounds checks. C1=1: conv1 7x7 pad=0 on
// packed [n][256][256][4] (ci padded to 4; fake taps have zero weights).
// POOL=1: quad-ordered M, fused 2x2 maxpool. Writes NHWC raw/pooled fp32 +
// per-block per-channel (sum,sumsq) partials.
// BM=64, BN=64, BK=32; 256 thr = 4 waves; 3 MFMA per 16x16 tile (hi*hi +
// lo*hi + hi*lo). Frag: A row=lane&15, k=(lane>>4)*8+j; C/D col=lane&15,
// row=(lane>>4)*4+reg [HW-verified m89].
// ---------------------------------------------------------------------------
template<int POOL, int C1>
__global__ __launch_bounds__(256) void conv_mfma(
    const __bf16* __restrict__ inH, const __bf16* __restrict__ inL, long inZstride,
    const __bf16* __restrict__ wtH, const __bf16* __restrict__ wtL,
    float* __restrict__ out, long outZstride, float2* __restrict__ part,
    int HinP, int WinP, int Hout, int Wout, int Cout, int M, int niter,
    int H2, int W2, int H2c, int W2c)
{
    __shared__ __align__(16) char smem[20480];
    __bf16* AsH = (__bf16*)smem;             // [64][40] bf16
    __bf16* AsL = (__bf16*)(smem + 5120);
    __bf16* BsH = (__bf16*)(smem + 10240);
    __bf16* BsL = (__bf16*)(smem + 15360);
    float2* red = (float2*)smem;             // [64][16] reuse after K loop

    const int tid   = threadIdx.x;
    const int mload = tid & 63;
    const int wv    = tid >> 6;
    const int ln15  = tid & 15;
    const int lhi   = (tid >> 4) & 3;

    const int mA = blockIdx.x * 64 + mload;
    int nb, h, w; bool mvalid;
    if (POOL) {
        int r = mA & 3, quad = mA >> 2;
        int cpi = H2c * W2c;
        nb = quad / cpi;
        int rem = quad - nb * cpi;
        int h2 = rem / W2c, w2 = rem - h2 * W2c;
        h = h2 * 2 + (r >> 1); w = w2 * 2 + (r & 1);
        mvalid = (mA < M) && (h < Hout) && (w < Wout);
    } else {
        int HW = Hout * Wout;
        mvalid = mA < M;
        int mm = mvalid ? mA : 0;
        nb = mm / HW;
        int rem = mm - nb * HW;
        h = rem / Wout; w = rem - h * Wout;
    }
    if (!mvalid) { nb = 0; h = 0; w = 0; }

    const __bf16* ipH = inH + (size_t)blockIdx.z * inZstride;
    const __bf16* ipL = inL + (size_t)blockIdx.z * inZstride;
    size_t base_m;
    if (C1) base_m = ((size_t)(nb * 256 + h) * 256 + w) * 4;
    else    base_m = ((size_t)(nb * HinP + h) * WinP + w) * 64;

    const __bf16* wpH = wtH + (size_t)blockIdx.z * niter * 2048;
    const __bf16* wpL = wtL + (size_t)blockIdx.z * niter * 2048;

    f32x4 acc[4] = {};
    bf16x8 arH, arL, brH, brL, zero8;
#pragma unroll
    for (int j = 0; j < 8; ++j) zero8[j] = (__bf16)0.0f;

    auto loadA = [&](int it) {
        int k0 = it * 32 + wv * 8;
        int off;
        if (C1) { off = (k0 >> 5) * 1024 + (k0 & 31); }
        else { int tap = k0 >> 6; int kh = tap / 3; int kw = tap - 3 * kh;
               off = (kh * WinP + kw) * 64 + (k0 & 63); }
        arH = *(const bf16x8*)(ipH + base_m + off);
        arL = *(const bf16x8*)(ipL + base_m + off);
        if (!C1 && !mvalid) { arH = zero8; arL = zero8; }
    };
    auto loadB = [&](int it) {
        size_t idx = (size_t)((it * 4 + wv) * 64 + mload) * 8;
        brH = *(const bf16x8*)(wpH + idx);
        brL = *(const bf16x8*)(wpL + idx);
    };

    loadA(0); loadB(0);
    for (int it = 0; it < niter; ++it) {
        __syncthreads();
        *(bf16x8*)&AsH[mload * 40 + wv * 8] = arH;
        *(bf16x8*)&AsL[mload * 40 + wv * 8] = arL;
        *(bf16x8*)&BsH[mload * 40 + wv * 8] = brH;
        *(bf16x8*)&BsL[mload * 40 + wv * 8] = brL;
        __syncthreads();
        if (it + 1 < niter) { loadA(it + 1); loadB(it + 1); }

        bf16x8 afH = *(const bf16x8*)&AsH[(wv * 16 + ln15) * 40 + lhi * 8];
        bf16x8 afL = *(const bf16x8*)&AsL[(wv * 16 + ln15) * 40 + lhi * 8];
#pragma unroll
        for (int t = 0; t < 4; ++t) {
            bf16x8 bH = *(const bf16x8*)&BsH[(t * 16 + ln15) * 40 + lhi * 8];
            bf16x8 bL = *(const bf16x8*)&BsL[(t * 16 + ln15) * 40 + lhi * 8];
            acc[t] = __builtin_amdgcn_mfma_f32_16x16x32_bf16(afH, bH, acc[t], 0, 0, 0);
            acc[t] = __builtin_amdgcn_mfma_f32_16x16x32_bf16(afL, bH, acc[t], 0, 0, 0);
            acc[t] = __builtin_amdgcn_mfma_f32_16x16x32_bf16(afH, bL, acc[t], 0, 0, 0);
        }
    }

    // ---- per-block per-channel (sum,sumsq) partials (invalid rows exact 0) ----
    __syncthreads();
#pragma unroll
    for (int t = 0; t < 4; ++t) {
        float s = 0.f, s2 = 0.f;
#pragma unroll
        for (int r = 0; r < 4; ++r) { float v = acc[t][r]; s += v; s2 += v * v; }
        red[(ln15 + 16 * t) * 16 + (wv * 4 + lhi)] = make_float2(s, s2);
    }
    __syncthreads();
    if (tid < 64) {
        float s = 0.f, s2 = 0.f;
#pragma unroll
        for (int q = 0; q < 16; ++q) { float2 v = red[tid * 16 + q]; s += v.x; s2 += v.y; }
        part[((size_t)blockIdx.z * 64 + tid) * gridDim.x + blockIdx.x] = make_float2(s, s2);
    }

    // ---- NHWC output ----
    float* zout = out + (size_t)blockIdx.z * outZstride;
    const int mbase = blockIdx.x * 64 + wv * 16 + lhi * 4;
    if (POOL) {
        if (mbase < M) {
            int quad = mbase >> 2;
            int cpi  = H2c * W2c;
            int nb2  = quad / cpi;
            int rem  = quad - nb2 * cpi;
            int h2 = rem / W2c, w2 = rem - h2 * W2c;
            if (h2 < H2 && w2 < W2) {
                float* op = zout + ((size_t)(nb2 * H2 + h2) * W2 + w2) * Cout;
#pragma unroll
                for (int t = 0; t < 4; ++t) {
                    int n = ln15 + 16 * t;
                    if (n < Cout) {
                        float mx = fmaxf(fmaxf(acc[t][0], acc[t][1]),
                                         fmaxf(acc[t][2], acc[t][3]));
                        op[n] = mx;
                    }
                }
            }
        }
    } else {
#pragma unroll
        for (int r = 0; r < 4; ++r) {
            int m = mbase + r;
            if (m < M) {
                float* op = zout + (size_t)m * Cout;
#pragma unroll
                for (int t = 0; t < 4; ++t) {
                    int n = ln15 + 16 * t;
                    if (n < Cout) op[n] = acc[t][r];
                }
            }
        }
    }
}

// partials -> (mean, rsqrt(var+eps)) per (z,channel)
__global__ __launch_bounds__(256) void bn_finalize(const float2* __restrict__ part,
                                                   int nblkx, double Ninv,
                                                   float2* __restrict__ stats)
{
    __shared__ double sh[512];
    const int zc = blockIdx.x, tid = threadIdx.x;
    const float2* p = part + (size_t)zc * nblkx;
    double s = 0, s2 = 0;
    for (int i = tid; i < nblkx; i += 256) { s += p[i].x; s2 += p[i].y; }
    sh[tid] = s; sh[256 + tid] = s2;
    __syncthreads();
    for (int st = 128; st > 0; st >>= 1) {
        if (tid < st) { sh[tid] += sh[tid + st]; sh[256 + tid] += sh[256 + tid + st]; }
        __syncthreads();
    }
    if (tid == 0) {
        float mean = (float)(sh[0] * Ninv);
        float var  = (float)(sh[256] * Ninv - (double)mean * (double)mean);
        if (var < 0.f) var = 0.f;
        stats[zc] = make_float2(mean, rsqrtf(var + 1e-5f));
    }
}

// raw NHWC fp32 + stats -> padded NHWC bf16 hi/lo with zero border.
// images NZ = Z*16; stats index = (img>>4)*64 + c.
__global__ void bn_split(const float* __restrict__ raw, const float2* __restrict__ stats,
                         __bf16* __restrict__ outH, __bf16* __restrict__ outL,
                         int H, int W, int total)
{
    int idx = blockIdx.x * 256 + threadIdx.x;
    if (idx >= total) return;
    const int Hp = H + 2, Wp = W + 2;
    int c4 = idx & 15;
    int t  = idx >> 4;
    int wp = t % Wp; t /= Wp;
    int hp = t % Hp; int img = t / Hp;
    size_t o = (((size_t)img * Hp + hp) * Wp + wp) * 64 + c4 * 4;
    bf16x4 hi, lo;
    if (hp == 0 || hp == Hp - 1 || wp == 0 || wp == Wp - 1) {
#pragma unroll
        for (int j = 0; j < 4; ++j) { hi[j] = (__bf16)0.f; lo[j] = (__bf16)0.f; }
    } else {
        float4 v = *(const float4*)(raw + (((size_t)img * H + (hp - 1)) * W + (wp - 1)) * 64 + c4 * 4);
        const float2* st = stats + (img >> 4) * 64 + c4 * 4;
        float vv[4] = {v.x, v.y, v.z, v.w};
#pragma unroll
        for (int j = 0; j < 4; ++j) {
            float2 s = st[j];
            float r = fmaxf((vv[j] - s.x) * s.y, 0.f);
            __bf16 hh = (__bf16)r;
            hi[j] = hh; lo[j] = (__bf16)(r - (float)hh);
        }
    }
    *(bf16x4*)(outH + o) = hi;
    *(bf16x4*)(outL + o) = lo;
}

// pooled NHWC [P][16][H][W][64] + stats + d -> XB padded hi/lo [C][16][Hp][Wp][64]
__global__ void mix_split(const float* __restrict__ pooled, const float2* __restrict__ stats,
                          const float* __restrict__ d,
                          __bf16* __restrict__ outH, __bf16* __restrict__ outL,
                          int H, int W, int P, long strideP, int total)
{
    int idx = blockIdx.x * 256 + threadIdx.x;
    if (idx >= total) return;
    const int Hp = H + 2, Wp = W + 2;
    int c4 = idx & 15;
    int t  = idx >> 4;
    int wp = t % Wp; t /= Wp;
    int hp = t % Hp; t /= Hp;
    int n  = t & 15;
    int cc = t >> 4;
    size_t o = (((size_t)(cc * 16 + n) * Hp + hp) * Wp + wp) * 64 + c4 * 4;
    bf16x4 hi, lo;
    if (hp == 0 || hp == Hp - 1 || wp == 0 || wp == Wp - 1) {
#pragma unroll
        for (int j = 0; j < 4; ++j) { hi[j] = (__bf16)0.f; lo[j] = (__bf16)0.f; }
    } else {
        float a[4] = {0.f, 0.f, 0.f, 0.f};
        const float* pb = pooled + (((size_t)n * H + (hp - 1)) * W + (wp - 1)) * 64 + c4 * 4;
        for (int p = 0; p < P; ++p) {
            float4 v = *(const float4*)(pb + (size_t)p * strideP);
            const float2* st = stats + p * 64 + c4 * 4;
            float dc = d[cc * P + p];
            float vv[4] = {v.x, v.y, v.z, v.w};
#pragma unroll
            for (int j = 0; j < 4; ++j) {
                float2 s = st[j];
                a[j] = fmaf(dc, fmaxf((vv[j] - s.x) * s.y, 0.f), a[j]);
            }
        }
#pragma unroll
        for (int j = 0; j < 4; ++j) {
            __bf16 hh = (__bf16)a[j];
            hi[j] = hh; lo[j] = (__bf16)(a[j] - (float)hh);
        }
    }
    *(bf16x4*)(outH + o) = hi;
    *(bf16x4*)(outL + o) = lo;
}

// L3 mix: pooled [16][16][7][7][32] -> XB3 fp32 [40][16][7][7][32]
__global__ void mix_last(const float* __restrict__ pooled, const float2* __restrict__ stats,
                         const float* __restrict__ d, float* __restrict__ out, int total)
{
    int idx = blockIdx.x * 256 + threadIdx.x;
    if (idx >= total) return;
    int c  = idx & 31;
    int t  = idx >> 5;
    int hw = t % 49; t /= 49;
    int n  = t & 15;
    int a  = t >> 4;
    float acc = 0.f;
    const float* pb = pooled + ((size_t)n * 49 + hw) * 32 + c;
    for (int p = 0; p < 16; ++p) {
        float2 s = stats[p * 64 + c];
        acc = fmaf(d[a * 16 + p], fmaxf((pb[(size_t)p * 25088] - s.x) * s.y, 0.f), acc);
    }
    out[idx] = acc;
}

// x NCHW [16][3][256][256] -> packed NHWC4 hi/lo [16][256][256][4]
__global__ void prep_x(const float* __restrict__ x, __bf16* __restrict__ xH,
                       __bf16* __restrict__ xL)
{
    int idx = blockIdx.x * 256 + threadIdx.x;   // 16*65536
    if (idx >= 16 * 65536) return;
    int n = idx >> 16, hw = idx & 65535;
    bf16x4 hi, lo;
#pragma unroll
    for (int ci = 0; ci < 3; ++ci) {
        float v = x[((size_t)n * 3 + ci) * 65536 + hw];
        __bf16 hh = (__bf16)v;
        hi[ci] = hh; lo[ci] = (__bf16)(v - (float)hh);
    }
    hi[3] = (__bf16)0.f; lo[3] = (__bf16)0.f;
    *(bf16x4*)(xH + (size_t)idx * 4) = hi;
    *(bf16x4*)(xL + (size_t)idx * 4) = lo;
}

// conv1 weights [64][3][7][7] -> hi/lo panels [28 kblk][64][8], k=kh*32+kw*4+ci
__global__ void wtrans1(const float* __restrict__ w, __bf16* __restrict__ wH,
                        __bf16* __restrict__ wL)
{
    int i = blockIdx.x * 256 + threadIdx.x;
    if (i >= 28 * 512) return;
    int j = i & 7, n = (i >> 3) & 63, kb = i >> 9;
    int k = kb * 8 + j;
    int kh = k >> 5, r = k & 31, kw = r >> 2, ci = r & 3;
    float v = (kw < 7 && ci < 3) ? w[((n * 3 + ci) * 7 + kh) * 7 + kw] : 0.f;
    __bf16 hh = (__bf16)v;
    wH[i] = hh; wL[i] = (__bf16)(v - (float)hh);
}

// 3x3 weights [P][Cout][64][3][3] -> hi/lo panels [p][72 kblk][64][8],
// k = (kh*3+kw)*64 + ci
__global__ void wtrans3(const float* __restrict__ w, __bf16* __restrict__ wH,
                        __bf16* __restrict__ wL, int P, int Cout)
{
    int total = P * 72 * 512;
    for (int i = blockIdx.x * 256 + threadIdx.x; i < total; i += gridDim.x * 256) {
        int j = i & 7, n = (i >> 3) & 63, kb = (i >> 9) % 72, p = (i >> 9) / 72;
        int k = kb * 8 + j;
        int ci = k & 63, tap = k >> 6, kh = tap / 3, kw = tap - 3 * kh;
        float v = (n < Cout) ? w[(((size_t)(p * Cout + n)) * 64 + ci) * 9 + kh * 3 + kw] : 0.f;
        __bf16 hh = (__bf16)v;
        wH[i] = hh; wL[i] = (__bf16)(v - (float)hh);
    }
}

// d = softmax_p( log(softmax_p(br*2)) / t ) for all 4 layers
__global__ void dcalc(const float* __restrict__ br0, const float* __restrict__ br1,
                      const float* __restrict__ br2, const float* __restrict__ br3,
                      const void* __restrict__ tptr, float* __restrict__ D)
{
    const int L = blockIdx.x;
    const float* br; int C, P, off;
    if      (L == 0) { br = br0; C = 4;  P = 2;  off = 0;   }
    else if (L == 1) { br = br1; C = 8;  P = 4;  off = 8;   }
    else if (L == 2) { br = br2; C = 16; P = 8;  off = 40;  }
    else             { br = br3; C = 40; P = 16; off = 168; }
    int ti = *(const int*)tptr;
    float t = (ti > 0 && ti < 1000000) ? (float)ti : *(const float*)tptr;
    const int c = threadIdx.x;
    if (c >= C) return;
    float u[16];
    float mx = -1e30f;
#pragma unroll
    for (int p = 0; p < 16; ++p) if (p < P) { u[p] = br[c * P + p] * 2.0f; mx = fmaxf(mx, u[p]); }
    float se = 0.f;
#pragma unroll
    for (int p = 0; p < 16; ++p) if (p < P) se += expf(u[p] - mx);
    float lse = mx + logf(se);
    float mx2 = -1e30f;
#pragma unroll
    for (int p = 0; p < 16; ++p) if (p < P) { u[p] = (u[p] - lse) / t; mx2 = fmaxf(mx2, u[p]); }
    float se2 = 0.f;
#pragma unroll
    for (int p = 0; p < 16; ++p) if (p < P) { u[p] = expf(u[p] - mx2); se2 += u[p]; }
#pragma unroll
    for (int p = 0; p < 16; ++p) if (p < P) D[off + c * P + p] = u[p] / se2;
}

// h1[a,b,i] = relu( sum_f f[a,b,f]*fw1[a,f,i] + fb1[a,i] ); f stored (h,w,c),
// fw1 indexed (c,h,w)
__global__ __launch_bounds__(128) void fc1_k(const float* __restrict__ f,
                                             const float* __restrict__ w1,
                                             const float* __restrict__ b1,
                                             float* __restrict__ h1)
{
    const int a = blockIdx.x >> 4;
    const int b = blockIdx.x & 15;
    const int i = threadIdx.x;
    const float* fv = f + ((size_t)a * 16 + b) * 1568;
    const float* wv = w1 + (size_t)a * 1568 * 128 + i;
    float acc = b1[a * 128 + i];
    for (int hw = 0; hw < 49; ++hw)
        for (int c = 0; c < 32; ++c)
            acc = fmaf(fv[hw * 32 + c], wv[(size_t)(c * 49 + hw) * 128], acc);
    h1[((size_t)a * 16 + b) * 128 + i] = fmaxf(acc, 0.f);
}

__global__ __launch_bounds__(128) void fc23_k(const float* __restrict__ h1,
                                              const float* __restrict__ w2,
                                              const float* __restrict__ b2,
                                              const float* __restrict__ w3,
                                              const float* __restrict__ b3,
                                              float* __restrict__ out)
{
    __shared__ float sh1[16][128];
    __shared__ float sh2[16][128];
    const int a = blockIdx.x;
    const int i = threadIdx.x;
    for (int b = 0; b < 16; ++b) sh1[b][i] = h1[((size_t)a * 16 + b) * 128 + i];
    __syncthreads();
    float acc[16];
#pragma unroll
    for (int b = 0; b < 16; ++b) acc[b] = b2[a * 128 + i];
    for (int ff = 0; ff < 128; ++ff) {
        float wv = w2[((size_t)a * 128 + ff) * 128 + i];
#pragma unroll
        for (int b = 0; b < 16; ++b) acc[b] = fmaf(sh1[b][ff], wv, acc[b]);
    }
    for (int b = 0; b < 16; ++b) sh2[b][i] = fmaxf(acc[b], 0.f);
    __syncthreads();
    if (i < 16) {
        float o = b3[a];
        for (int ff = 0; ff < 128; ++ff) o = fmaf(sh2[i][ff], w3[a * 128 + ff], o);
        out[i * 40 + a] = o;
    }
}

extern "C" void kernel_launch(void* const* d_in, const int* in_sizes, int n_in,
                              void* d_out, int out_size, void* d_ws, size_t ws_size,
                              hipStream_t stream)
{
    (void)in_sizes; (void)n_in;

    const float* x   = (const float*)d_in[0];
    const float* w10 = (const float*)d_in[1];
    const float* wa[4] = {(const float*)d_in[3],  (const float*)d_in[7],
                          (const float*)d_in[11], (const float*)d_in[15]};
    const float* wb[4] = {(const float*)d_in[5],  (const float*)d_in[9],
                          (const float*)d_in[13], (const float*)d_in[17]};
    const float* br[4] = {(const float*)d_in[19], (const float*)d_in[20],
                          (const float*)d_in[21], (const float*)d_in[22]};
    const float* fw1 = (const float*)d_in[23];
    const float* fb1 = (const float*)d_in[24];
    const float* fw2 = (const float*)d_in[25];
    const float* fb2 = (const float*)d_in[26];
    const float* fw3 = (const float*)d_in[27];
    const float* fb3 = (const float*)d_in[28];
    float* out = (float*)d_out;

    const int Pl[4]  = {2, 4, 8, 16};
    const int CBs[4] = {64, 64, 64, 32};

    // ---- workspace arenas (f32 units); total 60,264,704 f32 = 241.06 MB ----
    const size_t NEED = 60264704ull * 4ull;
    if (ws_size < NEED) {
        hipMemsetAsync(d_out, 0, (size_t)out_size * sizeof(float), stream);
        return;
    }
    float* ws = (float*)d_ws;
    size_t o = 0;
    __bf16* WT1H = (__bf16*)(ws + o); o += 7168;   // 14336 bf16
    __bf16* WT1L = (__bf16*)(ws + o); o += 7168;
    __bf16 *WTAH[4], *WTAL[4], *WTBH[4], *WTBL[4];
    for (int L = 0; L < 4; ++L) {                  // P*72*512 bf16 each
        WTAH[L] = (__bf16*)(ws + o); o += (size_t)Pl[L] * 18432;
        WTAL[L] = (__bf16*)(ws + o); o += (size_t)Pl[L] * 18432;
        WTBH[L] = (__bf16*)(ws + o); o += (size_t)Pl[L] * 18432;
        WTBL[L] = (__bf16*)(ws + o); o += (size_t)Pl[L] * 18432;
    }
    float*  D     = ws + o; o += 1024;
    float2* STATS = (float2*)(ws + o); o += 4352;
    float2* STATS_C1 = STATS;
    float2* STATS_A  = STATS + 64;
    float2* STATS_B  = STATS + 1088;
    float*  H1 = ws + o; o += 81920;
    float*  A6 = ws + o; o += 524288;      // small conv partials
    float*  A5 = ws + o; o += 7872512;     // pooled raw / conv1 partials
    float*  A4 = ws + o; o += 16000000;    // raw conv outputs (fp32 NHWC)
    float*  A3 = ws + o; o += 16777216;    // split bufs (hi/lo bf16) / xc
    float*  A2 = ws + o; o += 16777216;    // Y / XB chain

    float2* PART   = (float2*)A6;
    float2* PARTC1 = (float2*)A5;
    __bf16* xcH = (__bf16*)A3;
    __bf16* xcL = (__bf16*)(A3 + 2097152);
    __bf16* A2H = (__bf16*)A2;             // hi at A2[0:], lo after
    __bf16* A2L = (__bf16*)(A2 + 8388608);
    __bf16* A3H = (__bf16*)A3;
    __bf16* A3L = (__bf16*)(A3 + 8388608);

    // ---- weights + mix coefficients + conv1 input prep ----
    prep_x<<<4096, 256, 0, stream>>>(x, xcH, xcL);
    wtrans1<<<56, 256, 0, stream>>>(w10, WT1H, WT1L);
    for (int L = 0; L < 4; ++L) {
        int tA = Pl[L] * 72 * 512;
        wtrans3<<<DIVUP(tA, 256), 256, 0, stream>>>(wa[L], WTAH[L], WTAL[L], Pl[L], 64);
        wtrans3<<<DIVUP(tA, 256), 256, 0, stream>>>(wb[L], WTBH[L], WTBL[L], Pl[L], CBs[L]);
    }
    dcalc<<<4, 64, 0, stream>>>(br[0], br[1], br[2], br[3], d_in[29], D);

    // ---- conv1: xc -> pooled raw A4 [16,125,125,64] + stats ----
    conv_mfma<1, 1><<<dim3(15625, 1, 1), 256, 0, stream>>>(
        xcH, xcL, 0, WT1H, WT1L, A4, 0, PARTC1,
        256, 256, 250, 250, 64, 1000000, 7, 125, 125, 125, 125);
    bn_finalize<<<64, 256, 0, stream>>>(PARTC1, 15625, 1.0 / 1000000.0, STATS_C1);
    // Y = bn_split(A4) -> A2 padded [16][127][127][64]
    bn_split<<<DIVUP(16 * 127 * 127 * 16, 256), 256, 0, stream>>>(
        A4, STATS_C1, A2H, A2L, 125, 125, 16 * 127 * 127 * 16);

    // ---- layer 0 (per parent; Y shared) ----
    for (int p = 0; p < 2; ++p) {
        conv_mfma<0, 0><<<dim3(3907, 1, 1), 256, 0, stream>>>(
            A2H, A2L, 0, WTAH[0] + (size_t)p * 36864, WTAL[0] + (size_t)p * 36864,
            A4, 0, PART, 127, 127, 125, 125, 64, 250000, 18, 0, 0, 1, 1);
        bn_finalize<<<64, 256, 0, stream>>>(PART, 3907, 1.0 / 250000.0, STATS_A);
        bn_split<<<DIVUP(16 * 127 * 127 * 16, 256), 256, 0, stream>>>(
            A4, STATS_A, A3H, A3L, 125, 125, 16 * 127 * 127 * 16);
        conv_mfma<1, 0><<<dim3(3969, 1, 1), 256, 0, stream>>>(
            A3H, A3L, 0, WTBH[0] + (size_t)p * 36864, WTBL[0] + (size_t)p * 36864,
            A5 + (size_t)p * 3936256, 0, PART,
            127, 127, 125, 125, 64, 254016, 18, 62, 62, 63, 63);
        bn_finalize<<<64, 256, 0, stream>>>(PART, 3969, 1.0 / 250000.0, STATS_B + p * 64);
    }
    mix_split<<<DIVUP(4 * 16 * 64 * 64 * 16, 256), 256, 0, stream>>>(
        A5, STATS_B, D + 0, A2H, A2L, 62, 62, 2, 3936256, 4 * 16 * 64 * 64 * 16);

    // ---- layer 1 (z=4) ----
    conv_mfma<0, 0><<<dim3(961, 1, 4), 256, 0, stream>>>(
        A2H, A2L, 4194304, WTAH[1], WTAL[1], A4, 3936256, PART,
        64, 64, 62, 62, 64, 61504, 18, 0, 0, 1, 1);
    bn_finalize<<<256, 256, 0, stream>>>(PART, 961, 1.0 / 61504.0, STATS_A);
    bn_split<<<DIVUP(64 * 64 * 64 * 16, 256), 256, 0, stream>>>(
        A4, STATS_A, A3H, A3L, 62, 62, 64 * 64 * 64 * 16);
    conv_mfma<1, 0><<<dim3(961, 1, 4), 256, 0, stream>>>(
        A3H, A3L, 4194304, WTBH[1], WTBL[1], A5, 984064, PART,
        64, 64, 62, 62, 64, 61504, 18, 31, 31, 31, 31);
    bn_finalize<<<256, 256, 0, stream>>>(PART, 961, 1.0 / 61504.0, STATS_B);
    mix_split<<<DIVUP(8 * 16 * 33 * 33 * 16, 256), 256, 0, stream>>>(
        A5, STATS_B, D + 8, A2H, A2L, 31, 31, 4, 984064, 8 * 16 * 33 * 33 * 16);

    // ---- layer 2 (z=8) ----
    conv_mfma<0, 0><<<dim3(241, 1, 8), 256, 0, stream>>>(
        A2H, A2L, 1115136, WTAH[2], WTAL[2], A4, 984064, PART,
        33, 33, 31, 31, 64, 15376, 18, 0, 0, 1, 1);
    bn_finalize<<<512, 256, 0, stream>>>(PART, 241, 1.0 / 15376.0, STATS_A);
    bn_split<<<DIVUP(128 * 33 * 33 * 16, 256), 256, 0, stream>>>(
        A4, STATS_A, A3H, A3L, 31, 31, 128 * 33 * 33 * 16);
    conv_mfma<1, 0><<<dim3(256, 1, 8), 256, 0, stream>>>(
        A3H, A3L, 1115136, WTBH[2], WTBL[2], A5, 230400, PART,
        33, 33, 31, 31, 64, 16384, 18, 15, 15, 16, 16);
    bn_finalize<<<512, 256, 0, stream>>>(PART, 256, 1.0 / 15376.0, STATS_B);
    mix_split<<<DIVUP(16 * 16 * 17 * 17 * 16, 256), 256, 0, stream>>>(
        A5, STATS_B, D + 40, A2H, A2L, 15, 15, 8, 230400, 16 * 16 * 17 * 17 * 16);

    // ---- layer 3 (z=16) ----
    conv_mfma<0, 0><<<dim3(57, 1, 16), 256, 0, stream>>>(
        A2H, A2L, 295936, WTAH[3], WTAL[3], A4, 230400, PART,
        17, 17, 15, 15, 64, 3600, 18, 0, 0, 1, 1);
    bn_finalize<<<1024, 256, 0, stream>>>(PART, 57, 1.0 / 3600.0, STATS_A);
    bn_split<<<DIVUP(256 * 17 * 17 * 16, 256), 256, 0, stream>>>(
        A4, STATS_A, A3H, A3L, 15, 15, 256 * 17 * 17 * 16);
    conv_mfma<1, 0><<<dim3(64, 1, 16), 256, 0, stream>>>(
        A3H, A3L, 295936, WTBH[3], WTBL[3], A5, 25088, PART,
        17, 17, 15, 15, 32, 4096, 18, 7, 7, 8, 8);
    bn_finalize<<<1024, 256, 0, stream>>>(PART, 64, 1.0 / 3600.0, STATS_B);
    mix_last<<<DIVUP(40 * 16 * 49 * 32, 256), 256, 0, stream>>>(
        A5, STATS_B, D + 168, A2, 40 * 16 * 49 * 32);

    // ---- FC heads ----
    fc1_k<<<640, 128, 0, stream>>>(A2, fw1, fb1, H1);
    fc23_k<<<40, 128, 0, stream>>>(H1, fw2, fb2, fw3, fb3, out);
}

// Round 6
// 1305.482 us; speedup vs baseline: 2.5673x; 1.0290x over previous
//
#include <hip/hip_runtime.h>
#include <math.h>

#define DIVUP(a,b) (((a)+(b)-1)/(b))

typedef __bf16 bf16x8 __attribute__((ext_vector_type(8)));
typedef __bf16 bf16x4 __attribute__((ext_vector_type(4)));
typedef float  f32x4  __attribute__((ext_vector_type(4)));

// ---------------------------------------------------------------------------
// Implicit-GEMM conv, NHWC, split-bf16 3-MFMA (fp32-grade accuracy).
// BM=128, BN=64, BK=32; 256 thr = 4 waves; wave w owns rows [32w,32w+32),
// 24 MFMA per K-step (2 row-tiles x 4 col-tiles x 3 split terms).
// C1=0: 3x3 pad=1 on zero-bordered [*][HinP][WinP][64]; C1=1: conv1 7x7 pad=0
// on packed [n][256][256][4]. POOL=1: quad-ordered M + fused 2x2 maxpool.
// Also emits per-block per-channel (sum,sumsq) partials (invalid rows = 0).
// Frag: A row=lane&15, k=(lane>>4)*8+j; C/D col=lane&15, row=(lane>>4)*4+reg.
// ---------------------------------------------------------------------------
template<int POOL, int C1>
__global__ __launch_bounds__(256) void conv_mfma(
    const __bf16* __restrict__ inH, const __bf16* __restrict__ inL, long inZstride,
    const __bf16* __restrict__ wtH, const __bf16* __restrict__ wtL,
    float* __restrict__ out, long outZstride, float2* __restrict__ part,
    int HinP, int WinP, int Hout, int Wout, int Cout, int M, int niter,
    int H2, int W2, int H2c, int W2c)
{
    __shared__ __align__(16) char smem[30720];
    __bf16* AsH = (__bf16*)smem;              // [128][40] bf16
    __bf16* AsL = (__bf16*)(smem + 10240);
    __bf16* BsH = (__bf16*)(smem + 20480);    // [64][40]
    __bf16* BsL = (__bf16*)(smem + 25600);
    float2* red = (float2*)smem;              // [64][17] reuse after K loop

    const int tid   = threadIdx.x;
    const int mload = tid & 63;
    const int wv    = tid >> 6;
    const int ln15  = tid & 15;
    const int lhi   = (tid >> 4) & 3;

    const __bf16* ipH = inH + (size_t)blockIdx.z * inZstride;
    const __bf16* ipL = inL + (size_t)blockIdx.z * inZstride;

    auto geom = [&](int mA, size_t& base, bool& valid) {
        int nb, h, w;
        if (POOL) {
            int r = mA & 3, quad = mA >> 2;
            int cpi = H2c * W2c;
            nb = quad / cpi;
            int rem = quad - nb * cpi;
            int h2 = rem / W2c, w2 = rem - h2 * W2c;
            h = h2 * 2 + (r >> 1); w = w2 * 2 + (r & 1);
            valid = (mA < M) && (h < Hout) && (w < Wout);
        } else {
            int HW = Hout * Wout;
            valid = mA < M;
            int mm = valid ? mA : 0;
            nb = mm / HW;
            int rem = mm - nb * HW;
            h = rem / Wout; w = rem - h * Wout;
        }
        if (!valid) { nb = 0; h = 0; w = 0; }
        if (C1) base = ((size_t)(nb * 256 + h) * 256 + w) * 4;
        else    base = ((size_t)(nb * HinP + h) * WinP + w) * 64;
    };

    size_t base0, base1; bool mv0, mv1;
    geom(blockIdx.x * 128 + mload, base0, mv0);
    geom(blockIdx.x * 128 + 64 + mload, base1, mv1);

    const __bf16* wpH = wtH + (size_t)blockIdx.z * niter * 2048;
    const __bf16* wpL = wtL + (size_t)blockIdx.z * niter * 2048;

    f32x4 acc[2][4] = {};
    bf16x8 arH0, arL0, arH1, arL1, brH, brL, zero8;
#pragma unroll
    for (int j = 0; j < 8; ++j) zero8[j] = (__bf16)0.0f;

    auto loadA = [&](int it) {
        int k0 = it * 32 + wv * 8;
        int off;
        if (C1) { off = (k0 >> 5) * 1024 + (k0 & 31); }
        else { int tap = k0 >> 6; int kh = tap / 3; int kw = tap - 3 * kh;
               off = (kh * WinP + kw) * 64 + (k0 & 63); }
        arH0 = *(const bf16x8*)(ipH + base0 + off);
        arL0 = *(const bf16x8*)(ipL + base0 + off);
        arH1 = *(const bf16x8*)(ipH + base1 + off);
        arL1 = *(const bf16x8*)(ipL + base1 + off);
        if (!mv0) { arH0 = zero8; arL0 = zero8; }
        if (!mv1) { arH1 = zero8; arL1 = zero8; }
    };
    auto loadB = [&](int it) {
        size_t idx = (size_t)((it * 4 + wv) * 64 + mload) * 8;
        brH = *(const bf16x8*)(wpH + idx);
        brL = *(const bf16x8*)(wpL + idx);
    };

    loadA(0); loadB(0);
    for (int it = 0; it < niter; ++it) {
        __syncthreads();
        *(bf16x8*)&AsH[mload * 40 + wv * 8] = arH0;
        *(bf16x8*)&AsL[mload * 40 + wv * 8] = arL0;
        *(bf16x8*)&AsH[(64 + mload) * 40 + wv * 8] = arH1;
        *(bf16x8*)&AsL[(64 + mload) * 40 + wv * 8] = arL1;
        *(bf16x8*)&BsH[mload * 40 + wv * 8] = brH;
        *(bf16x8*)&BsL[mload * 40 + wv * 8] = brL;
        __syncthreads();
        if (it + 1 < niter) { loadA(it + 1); loadB(it + 1); }

        bf16x8 afH[2], afL[2];
#pragma unroll
        for (int q = 0; q < 2; ++q) {
            afH[q] = *(const bf16x8*)&AsH[(wv * 32 + q * 16 + ln15) * 40 + lhi * 8];
            afL[q] = *(const bf16x8*)&AsL[(wv * 32 + q * 16 + ln15) * 40 + lhi * 8];
        }
#pragma unroll
        for (int t = 0; t < 4; ++t) {
            bf16x8 bH = *(const bf16x8*)&BsH[(t * 16 + ln15) * 40 + lhi * 8];
            bf16x8 bL = *(const bf16x8*)&BsL[(t * 16 + ln15) * 40 + lhi * 8];
#pragma unroll
            for (int q = 0; q < 2; ++q) {
                acc[q][t] = __builtin_amdgcn_mfma_f32_16x16x32_bf16(afH[q], bH, acc[q][t], 0, 0, 0);
                acc[q][t] = __builtin_amdgcn_mfma_f32_16x16x32_bf16(afL[q], bH, acc[q][t], 0, 0, 0);
                acc[q][t] = __builtin_amdgcn_mfma_f32_16x16x32_bf16(afH[q], bL, acc[q][t], 0, 0, 0);
            }
        }
    }

    // ---- per-block per-channel (sum,sumsq) partials ----
    __syncthreads();
#pragma unroll
    for (int t = 0; t < 4; ++t) {
        float s = 0.f, s2 = 0.f;
#pragma unroll
        for (int q = 0; q < 2; ++q)
#pragma unroll
            for (int r = 0; r < 4; ++r) { float v = acc[q][t][r]; s += v; s2 += v * v; }
        red[(ln15 + 16 * t) * 17 + (wv * 4 + lhi)] = make_float2(s, s2);
    }
    __syncthreads();
    if (tid < 64) {
        float s = 0.f, s2 = 0.f;
#pragma unroll
        for (int q = 0; q < 16; ++q) { float2 v = red[tid * 17 + q]; s += v.x; s2 += v.y; }
        part[((size_t)blockIdx.z * 64 + tid) * gridDim.x + blockIdx.x] = make_float2(s, s2);
    }

    // ---- NHWC output ----
    float* zout = out + (size_t)blockIdx.z * outZstride;
#pragma unroll
    for (int q = 0; q < 2; ++q) {
        const int mbase = blockIdx.x * 128 + wv * 32 + q * 16 + lhi * 4;
        if (POOL) {
            if (mbase < M) {
                int quad = mbase >> 2;
                int cpi  = H2c * W2c;
                int nb2  = quad / cpi;
                int rem  = quad - nb2 * cpi;
                int h2 = rem / W2c, w2 = rem - h2 * W2c;
                if (h2 < H2 && w2 < W2) {
                    float* op = zout + ((size_t)(nb2 * H2 + h2) * W2 + w2) * Cout;
#pragma unroll
                    for (int t = 0; t < 4; ++t) {
                        int n = ln15 + 16 * t;
                        if (n < Cout) {
                            float mx = fmaxf(fmaxf(acc[q][t][0], acc[q][t][1]),
                                             fmaxf(acc[q][t][2], acc[q][t][3]));
                            op[n] = mx;
                        }
                    }
                }
            }
        } else {
#pragma unroll
            for (int r = 0; r < 4; ++r) {
                int m = mbase + r;
                if (m < M) {
                    float* op = zout + (size_t)m * Cout;
#pragma unroll
                    for (int t = 0; t < 4; ++t) {
                        int n = ln15 + 16 * t;
                        if (n < Cout) op[n] = acc[q][t][r];
                    }
                }
            }
        }
    }
}

// partials -> (mean, rsqrt(var+eps)) per (z,channel)
__global__ __launch_bounds__(256) void bn_finalize(const float2* __restrict__ part,
                                                   int nblkx, double Ninv,
                                                   float2* __restrict__ stats)
{
    __shared__ double sh[512];
    const int zc = blockIdx.x, tid = threadIdx.x;
    const float2* p = part + (size_t)zc * nblkx;
    double s = 0, s2 = 0;
    for (int i = tid; i < nblkx; i += 256) { s += p[i].x; s2 += p[i].y; }
    sh[tid] = s; sh[256 + tid] = s2;
    __syncthreads();
    for (int st = 128; st > 0; st >>= 1) {
        if (tid < st) { sh[tid] += sh[tid + st]; sh[256 + tid] += sh[256 + tid + st]; }
        __syncthreads();
    }
    if (tid == 0) {
        float mean = (float)(sh[0] * Ninv);
        float var  = (float)(sh[256] * Ninv - (double)mean * (double)mean);
        if (var < 0.f) var = 0.f;
        stats[zc] = make_float2(mean, rsqrtf(var + 1e-5f));
    }
}

// raw NHWC fp32 + stats -> padded NHWC bf16 hi/lo with zero border.
__global__ void bn_split(const float* __restrict__ raw, const float2* __restrict__ stats,
                         __bf16* __restrict__ outH, __bf16* __restrict__ outL,
                         int H, int W, int total)
{
    int idx = blockIdx.x * 256 + threadIdx.x;
    if (idx >= total) return;
    const int Hp = H + 2, Wp = W + 2;
    int c4 = idx & 15;
    int t  = idx >> 4;
    int wp = t % Wp; t /= Wp;
    int hp = t % Hp; int img = t / Hp;
    size_t o = (((size_t)img * Hp + hp) * Wp + wp) * 64 + c4 * 4;
    bf16x4 hi, lo;
    if (hp == 0 || hp == Hp - 1 || wp == 0 || wp == Wp - 1) {
#pragma unroll
        for (int j = 0; j < 4; ++j) { hi[j] = (__bf16)0.f; lo[j] = (__bf16)0.f; }
    } else {
        float4 v = *(const float4*)(raw + (((size_t)img * H + (hp - 1)) * W + (wp - 1)) * 64 + c4 * 4);
        const float2* st = stats + (img >> 4) * 64 + c4 * 4;
        float vv[4] = {v.x, v.y, v.z, v.w};
#pragma unroll
        for (int j = 0; j < 4; ++j) {
            float2 s = st[j];
            float r = fmaxf((vv[j] - s.x) * s.y, 0.f);
            __bf16 hh = (__bf16)r;
            hi[j] = hh; lo[j] = (__bf16)(r - (float)hh);
        }
    }
    *(bf16x4*)(outH + o) = hi;
    *(bf16x4*)(outL + o) = lo;
}

// pooled NHWC [P][16][H][W][64] + stats + d -> XB padded hi/lo [C][16][Hp][Wp][64]
__global__ void mix_split(const float* __restrict__ pooled, const float2* __restrict__ stats,
                          const float* __restrict__ d,
                          __bf16* __restrict__ outH, __bf16* __restrict__ outL,
                          int H, int W, int P, long strideP, int total)
{
    int idx = blockIdx.x * 256 + threadIdx.x;
    if (idx >= total) return;
    const int Hp = H + 2, Wp = W + 2;
    int c4 = idx & 15;
    int t  = idx >> 4;
    int wp = t % Wp; t /= Wp;
    int hp = t % Hp; t /= Hp;
    int n  = t & 15;
    int cc = t >> 4;
    size_t o = (((size_t)(cc * 16 + n) * Hp + hp) * Wp + wp) * 64 + c4 * 4;
    bf16x4 hi, lo;
    if (hp == 0 || hp == Hp - 1 || wp == 0 || wp == Wp - 1) {
#pragma unroll
        for (int j = 0; j < 4; ++j) { hi[j] = (__bf16)0.f; lo[j] = (__bf16)0.f; }
    } else {
        float a[4] = {0.f, 0.f, 0.f, 0.f};
        const float* pb = pooled + (((size_t)n * H + (hp - 1)) * W + (wp - 1)) * 64 + c4 * 4;
        for (int p = 0; p < P; ++p) {
            float4 v = *(const float4*)(pb + (size_t)p * strideP);
            const float2* st = stats + p * 64 + c4 * 4;
            float dc = d[cc * P + p];
            float vv[4] = {v.x, v.y, v.z, v.w};
#pragma unroll
            for (int j = 0; j < 4; ++j) {
                float2 s = st[j];
                a[j] = fmaf(dc, fmaxf((vv[j] - s.x) * s.y, 0.f), a[j]);
            }
        }
#pragma unroll
        for (int j = 0; j < 4; ++j) {
            __bf16 hh = (__bf16)a[j];
            hi[j] = hh; lo[j] = (__bf16)(a[j] - (float)hh);
        }
    }
    *(bf16x4*)(outH + o) = hi;
    *(bf16x4*)(outL + o) = lo;
}

// L3 mix: pooled [16][16][7][7][32] -> XB3 fp32 [40][16][7][7][32]
__global__ void mix_last(const float* __restrict__ pooled, const float2* __restrict__ stats,
                         const float* __restrict__ d, float* __restrict__ out, int total)
{
    int idx = blockIdx.x * 256 + threadIdx.x;
    if (idx >= total) return;
    int c  = idx & 31;
    int t  = idx >> 5;
    int hw = t % 49; t /= 49;
    int n  = t & 15;
    int a  = t >> 4;
    float acc = 0.f;
    const float* pb = pooled + ((size_t)n * 49 + hw) * 32 + c;
    for (int p = 0; p < 16; ++p) {
        float2 s = stats[p * 64 + c];
        acc = fmaf(d[a * 16 + p], fmaxf((pb[(size_t)p * 25088] - s.x) * s.y, 0.f), acc);
    }
    out[idx] = acc;
}

// x NCHW [16][3][256][256] -> packed NHWC4 hi/lo [16][256][256][4]
__global__ void prep_x(const float* __restrict__ x, __bf16* __restrict__ xH,
                       __bf16* __restrict__ xL)
{
    int idx = blockIdx.x * 256 + threadIdx.x;   // 16*65536
    if (idx >= 16 * 65536) return;
    int n = idx >> 16, hw = idx & 65535;
    bf16x4 hi, lo;
#pragma unroll
    for (int ci = 0; ci < 3; ++ci) {
        float v = x[((size_t)n * 3 + ci) * 65536 + hw];
        __bf16 hh = (__bf16)v;
        hi[ci] = hh; lo[ci] = (__bf16)(v - (float)hh);
    }
    hi[3] = (__bf16)0.f; lo[3] = (__bf16)0.f;
    *(bf16x4*)(xH + (size_t)idx * 4) = hi;
    *(bf16x4*)(xL + (size_t)idx * 4) = lo;
}

// conv1 weights [64][3][7][7] -> hi/lo panels [28 kblk][64][8], k=kh*32+kw*4+ci
__global__ void wtrans1(const float* __restrict__ w, __bf16* __restrict__ wH,
                        __bf16* __restrict__ wL)
{
    int i = blockIdx.x * 256 + threadIdx.x;
    if (i >= 28 * 512) return;
    int j = i & 7, n = (i >> 3) & 63, kb = i >> 9;
    int k = kb * 8 + j;
    int kh = k >> 5, r = k & 31, kw = r >> 2, ci = r & 3;
    float v = (kw < 7 && ci < 3) ? w[((n * 3 + ci) * 7 + kh) * 7 + kw] : 0.f;
    __bf16 hh = (__bf16)v;
    wH[i] = hh; wL[i] = (__bf16)(v - (float)hh);
}

// 3x3 weights [P][Cout][64][3][3] -> hi/lo panels [p][72 kblk][64][8],
// k = (kh*3+kw)*64 + ci
__global__ void wtrans3(const float* __restrict__ w, __bf16* __restrict__ wH,
                        __bf16* __restrict__ wL, int P, int Cout)
{
    int total = P * 72 * 512;
    for (int i = blockIdx.x * 256 + threadIdx.x; i < total; i += gridDim.x * 256) {
        int j = i & 7, n = (i >> 3) & 63, kb = (i >> 9) % 72, p = (i >> 9) / 72;
        int k = kb * 8 + j;
        int ci = k & 63, tap = k >> 6, kh = tap / 3, kw = tap - 3 * kh;
        float v = (n < Cout) ? w[(((size_t)(p * Cout + n)) * 64 + ci) * 9 + kh * 3 + kw] : 0.f;
        __bf16 hh = (__bf16)v;
        wH[i] = hh; wL[i] = (__bf16)(v - (float)hh);
    }
}

// d = softmax_p( log(softmax_p(br*2)) / t ) for all 4 layers
__global__ void dcalc(const float* __restrict__ br0, const float* __restrict__ br1,
                      const float* __restrict__ br2, const float* __restrict__ br3,
                      const void* __restrict__ tptr, float* __restrict__ D)
{
    const int L = blockIdx.x;
    const float* br; int C, P, off;
    if      (L == 0) { br = br0; C = 4;  P = 2;  off = 0;   }
    else if (L == 1) { br = br1; C = 8;  P = 4;  off = 8;   }
    else if (L == 2) { br = br2; C = 16; P = 8;  off = 40;  }
    else             { br = br3; C = 40; P = 16; off = 168; }
    int ti = *(const int*)tptr;
    float t = (ti > 0 && ti < 1000000) ? (float)ti : *(const float*)tptr;
    const int c = threadIdx.x;
    if (c >= C) return;
    float u[16];
    float mx = -1e30f;
#pragma unroll
    for (int p = 0; p < 16; ++p) if (p < P) { u[p] = br[c * P + p] * 2.0f; mx = fmaxf(mx, u[p]); }
    float se = 0.f;
#pragma unroll
    for (int p = 0; p < 16; ++p) if (p < P) se += expf(u[p] - mx);
    float lse = mx + logf(se);
    float mx2 = -1e30f;
#pragma unroll
    for (int p = 0; p < 16; ++p) if (p < P) { u[p] = (u[p] - lse) / t; mx2 = fmaxf(mx2, u[p]); }
    float se2 = 0.f;
#pragma unroll
    for (int p = 0; p < 16; ++p) if (p < P) { u[p] = expf(u[p] - mx2); se2 += u[p]; }
#pragma unroll
    for (int p = 0; p < 16; ++p) if (p < P) D[off + c * P + p] = u[p] / se2;
}

// h1[a,b,i] = relu( sum_f f[a,b,f]*fw1[a,f,i] + fb1[a,i] ); f stored (h,w,c),
// fw1 indexed (c,h,w)
__global__ __launch_bounds__(128) void fc1_k(const float* __restrict__ f,
                                             const float* __restrict__ w1,
                                             const float* __restrict__ b1,
                                             float* __restrict__ h1)
{
    const int a = blockIdx.x >> 4;
    const int b = blockIdx.x & 15;
    const int i = threadIdx.x;
    const float* fv = f + ((size_t)a * 16 + b) * 1568;
    const float* wv = w1 + (size_t)a * 1568 * 128 + i;
    float acc = b1[a * 128 + i];
    for (int hw = 0; hw < 49; ++hw)
        for (int c = 0; c < 32; ++c)
            acc = fmaf(fv[hw * 32 + c], wv[(size_t)(c * 49 + hw) * 128], acc);
    h1[((size_t)a * 16 + b) * 128 + i] = fmaxf(acc, 0.f);
}

__global__ __launch_bounds__(128) void fc23_k(const float* __restrict__ h1,
                                              const float* __restrict__ w2,
                                              const float* __restrict__ b2,
                                              const float* __restrict__ w3,
                                              const float* __restrict__ b3,
                                              float* __restrict__ out)
{
    __shared__ float sh1[16][128];
    __shared__ float sh2[16][128];
    const int a = blockIdx.x;
    const int i = threadIdx.x;
    for (int b = 0; b < 16; ++b) sh1[b][i] = h1[((size_t)a * 16 + b) * 128 + i];
    __syncthreads();
    float acc[16];
#pragma unroll
    for (int b = 0; b < 16; ++b) acc[b] = b2[a * 128 + i];
    for (int ff = 0; ff < 128; ++ff) {
        float wv = w2[((size_t)a * 128 + ff) * 128 + i];
#pragma unroll
        for (int b = 0; b < 16; ++b) acc[b] = fmaf(sh1[b][ff], wv, acc[b]);
    }
    for (int b = 0; b < 16; ++b) sh2[b][i] = fmaxf(acc[b], 0.f);
    __syncthreads();
    if (i < 16) {
        float o = b3[a];
        for (int ff = 0; ff < 128; ++ff) o = fmaf(sh2[i][ff], w3[a * 128 + ff], o);
        out[i * 40 + a] = o;
    }
}

extern "C" void kernel_launch(void* const* d_in, const int* in_sizes, int n_in,
                              void* d_out, int out_size, void* d_ws, size_t ws_size,
                              hipStream_t stream)
{
    (void)in_sizes; (void)n_in;

    const float* x   = (const float*)d_in[0];
    const float* w10 = (const float*)d_in[1];
    const float* wa[4] = {(const float*)d_in[3],  (const float*)d_in[7],
                          (const float*)d_in[11], (const float*)d_in[15]};
    const float* wb[4] = {(const float*)d_in[5],  (const float*)d_in[9],
                          (const float*)d_in[13], (const float*)d_in[17]};
    const float* br[4] = {(const float*)d_in[19], (const float*)d_in[20],
                          (const float*)d_in[21], (const float*)d_in[22]};
    const float* fw1 = (const float*)d_in[23];
    const float* fb1 = (const float*)d_in[24];
    const float* fw2 = (const float*)d_in[25];
    const float* fb2 = (const float*)d_in[26];
    const float* fw3 = (const float*)d_in[27];
    const float* fb3 = (const float*)d_in[28];
    float* out = (float*)d_out;

    const int Pl[4]  = {2, 4, 8, 16};
    const int CBs[4] = {64, 64, 64, 32};

    // ---- workspace arenas (f32 units); total 60,264,704 f32 = 241.06 MB ----
    const size_t NEED = 60264704ull * 4ull;
    if (ws_size < NEED) {
        hipMemsetAsync(d_out, 0, (size_t)out_size * sizeof(float), stream);
        return;
    }
    float* ws = (float*)d_ws;
    size_t o = 0;
    __bf16* WT1H = (__bf16*)(ws + o); o += 7168;   // 14336 bf16
    __bf16* WT1L = (__bf16*)(ws + o); o += 7168;
    __bf16 *WTAH[4], *WTAL[4], *WTBH[4], *WTBL[4];
    for (int L = 0; L < 4; ++L) {                  // P*72*512 bf16 each
        WTAH[L] = (__bf16*)(ws + o); o += (size_t)Pl[L] * 18432;
        WTAL[L] = (__bf16*)(ws + o); o += (size_t)Pl[L] * 18432;
        WTBH[L] = (__bf16*)(ws + o); o += (size_t)Pl[L] * 18432;
        WTBL[L] = (__bf16*)(ws + o); o += (size_t)Pl[L] * 18432;
    }
    float*  D     = ws + o; o += 1024;
    float2* STATS = (float2*)(ws + o); o += 4352;
    float2* STATS_C1 = STATS;
    float2* STATS_A  = STATS + 64;
    float2* STATS_B  = STATS + 1088;
    float*  H1 = ws + o; o += 81920;
    float*  A6 = ws + o; o += 524288;      // small conv partials
    float*  A5 = ws + o; o += 7872512;     // pooled raw / conv1 partials
    float*  A4 = ws + o; o += 16000000;    // raw conv outputs (fp32 NHWC)
    float*  A3 = ws + o; o += 16777216;    // split bufs (hi/lo bf16) / xc
    float*  A2 = ws + o; o += 16777216;    // Y / XB chain

    float2* PART   = (float2*)A6;
    float2* PARTC1 = (float2*)A5;
    __bf16* xcH = (__bf16*)A3;
    __bf16* xcL = (__bf16*)(A3 + 2097152);
    __bf16* A2H = (__bf16*)A2;             // hi at A2[0:], lo after
    __bf16* A2L = (__bf16*)(A2 + 8388608);
    __bf16* A3H = (__bf16*)A3;
    __bf16* A3L = (__bf16*)(A3 + 8388608);

    // ---- weights + mix coefficients + conv1 input prep ----
    prep_x<<<4096, 256, 0, stream>>>(x, xcH, xcL);
    wtrans1<<<56, 256, 0, stream>>>(w10, WT1H, WT1L);
    for (int L = 0; L < 4; ++L) {
        int tA = Pl[L] * 72 * 512;
        wtrans3<<<DIVUP(tA, 256), 256, 0, stream>>>(wa[L], WTAH[L], WTAL[L], Pl[L], 64);
        wtrans3<<<DIVUP(tA, 256), 256, 0, stream>>>(wb[L], WTBH[L], WTBL[L], Pl[L], CBs[L]);
    }
    dcalc<<<4, 64, 0, stream>>>(br[0], br[1], br[2], br[3], d_in[29], D);

    // ---- conv1: xc -> pooled raw A4 [16,125,125,64] + stats ----
    conv_mfma<1, 1><<<dim3(7813, 1, 1), 256, 0, stream>>>(
        xcH, xcL, 0, WT1H, WT1L, A4, 0, PARTC1,
        256, 256, 250, 250, 64, 1000000, 7, 125, 125, 125, 125);
    bn_finalize<<<64, 256, 0, stream>>>(PARTC1, 7813, 1.0 / 1000000.0, STATS_C1);
    // Y = bn_split(A4) -> A2 padded [16][127][127][64]
    bn_split<<<DIVUP(16 * 127 * 127 * 16, 256), 256, 0, stream>>>(
        A4, STATS_C1, A2H, A2L, 125, 125, 16 * 127 * 127 * 16);

    // ---- layer 0 (per parent; Y shared) ----
    for (int p = 0; p < 2; ++p) {
        conv_mfma<0, 0><<<dim3(1954, 1, 1), 256, 0, stream>>>(
            A2H, A2L, 0, WTAH[0] + (size_t)p * 36864, WTAL[0] + (size_t)p * 36864,
            A4, 0, PART, 127, 127, 125, 125, 64, 250000, 18, 0, 0, 1, 1);
        bn_finalize<<<64, 256, 0, stream>>>(PART, 1954, 1.0 / 250000.0, STATS_A);
        bn_split<<<DIVUP(16 * 127 * 127 * 16, 256), 256, 0, stream>>>(
            A4, STATS_A, A3H, A3L, 125, 125, 16 * 127 * 127 * 16);
        conv_mfma<1, 0><<<dim3(1985, 1, 1), 256, 0, stream>>>(
            A3H, A3L, 0, WTBH[0] + (size_t)p * 36864, WTBL[0] + (size_t)p * 36864,
            A5 + (size_t)p * 3936256, 0, PART,
            127, 127, 125, 125, 64, 254016, 18, 62, 62, 63, 63);
        bn_finalize<<<64, 256, 0, stream>>>(PART, 1985, 1.0 / 250000.0, STATS_B + p * 64);
    }
    mix_split<<<DIVUP(4 * 16 * 64 * 64 * 16, 256), 256, 0, stream>>>(
        A5, STATS_B, D + 0, A2H, A2L, 62, 62, 2, 3936256, 4 * 16 * 64 * 64 * 16);

    // ---- layer 1 (z=4) ----
    conv_mfma<0, 0><<<dim3(481, 1, 4), 256, 0, stream>>>(
        A2H, A2L, 4194304, WTAH[1], WTAL[1], A4, 3936256, PART,
        64, 64, 62, 62, 64, 61504, 18, 0, 0, 1, 1);
    bn_finalize<<<256, 256, 0, stream>>>(PART, 481, 1.0 / 61504.0, STATS_A);
    bn_split<<<DIVUP(64 * 64 * 64 * 16, 256), 256, 0, stream>>>(
        A4, STATS_A, A3H, A3L, 62, 62, 64 * 64 * 64 * 16);
    conv_mfma<1, 0><<<dim3(481, 1, 4), 256, 0, stream>>>(
        A3H, A3L, 4194304, WTBH[1], WTBL[1], A5, 984064, PART,
        64, 64, 62, 62, 64, 61504, 18, 31, 31, 31, 31);
    bn_finalize<<<256, 256, 0, stream>>>(PART, 481, 1.0 / 61504.0, STATS_B);
    mix_split<<<DIVUP(8 * 16 * 33 * 33 * 16, 256), 256, 0, stream>>>(
        A5, STATS_B, D + 8, A2H, A2L, 31, 31, 4, 984064, 8 * 16 * 33 * 33 * 16);

    // ---- layer 2 (z=8) ----
    conv_mfma<0, 0><<<dim3(121, 1, 8), 256, 0, stream>>>(
        A2H, A2L, 1115136, WTAH[2], WTAL[2], A4, 984064, PART,
        33, 33, 31, 31, 64, 15376, 18, 0, 0, 1, 1);
    bn_finalize<<<512, 256, 0, stream>>>(PART, 121, 1.0 / 15376.0, STATS_A);
    bn_split<<<DIVUP(128 * 33 * 33 * 16, 256), 256, 0, stream>>>(
        A4, STATS_A, A3H, A3L, 31, 31, 128 * 33 * 33 * 16);
    conv_mfma<1, 0><<<dim3(128, 1, 8), 256, 0, stream>>>(
        A3H, A3L, 1115136, WTBH[2], WTBL[2], A5, 230400, PART,
        33, 33, 31, 31, 64, 16384, 18, 15, 15, 16, 16);
    bn_finalize<<<512, 256, 0, stream>>>(PART, 128, 1.0 / 15376.0, STATS_B);
    mix_split<<<DIVUP(16 * 16 * 17 * 17 * 16, 256), 256, 0, stream>>>(
        A5, STATS_B, D + 40, A2H, A2L, 15, 15, 8, 230400, 16 * 16 * 17 * 17 * 16);

    // ---- layer 3 (z=16) ----
    conv_mfma<0, 0><<<dim3(29, 1, 16), 256, 0, stream>>>(
        A2H, A2L, 295936, WTAH[3], WTAL[3], A4, 230400, PART,
        17, 17, 15, 15, 64, 3600, 18, 0, 0, 1, 1);
    bn_finalize<<<1024, 256, 0, stream>>>(PART, 29, 1.0 / 3600.0, STATS_A);
    bn_split<<<DIVUP(256 * 17 * 17 * 16, 256), 256, 0, stream>>>(
        A4, STATS_A, A3H, A3L, 15, 15, 256 * 17 * 17 * 16);
    conv_mfma<1, 0><<<dim3(32, 1, 16), 256, 0, stream>>>(
        A3H, A3L, 295936, WTBH[3], WTBL[3], A5, 25088, PART,
        17, 17, 15, 15, 32, 4096, 18, 7, 7, 8, 8);
    bn_finalize<<<1024, 256, 0, stream>>>(PART, 32, 1.0 / 3600.0, STATS_B);
    mix_last<<<DIVUP(40 * 16 * 49 * 32, 256), 256, 0, stream>>>(
        A5, STATS_B, D + 168, A2, 40 * 16 * 49 * 32);

    // ---- FC heads ----
    fc1_k<<<640, 128, 0, stream>>>(A2, fw1, fb1, H1);
    fc23_k<<<40, 128, 0, stream>>>(H1, fw2, fb2, fw3, fb3, out);
}

// Round 7
// 1206.223 us; speedup vs baseline: 2.7786x; 1.0823x over previous
//
#include <hip/hip_runtime.h>
#include <math.h>

#define DIVUP(a,b) (((a)+(b)-1)/(b))

typedef __bf16 bf16x8 __attribute__((ext_vector_type(8)));
typedef __bf16 bf16x4 __attribute__((ext_vector_type(4)));
typedef float  f32x4  __attribute__((ext_vector_type(4)));

// ---------------------------------------------------------------------------
// Implicit-GEMM conv, NHWC, split-bf16 3-MFMA (fp32-grade accuracy).
// BM=128, BN=64, BK=32; 256 thr = 4 waves; wave w owns rows [32w,32w+32),
// 24 MFMA per K-step. XCD-aware bijective block swizzle (m204): each XCD gets
// a contiguous chunk of m-tiles -> tap/row overlap hits the XCD-local L2.
// C1=0: 3x3 pad=1 on zero-bordered [*][HinP][WinP][64]; C1=1: conv1 7x7 pad=0
// on packed [n][256][256][4]. POOL=1: quad-ordered M + fused 2x2 maxpool.
// Also emits per-block per-channel (sum,sumsq) partials (invalid rows = 0).
// Frag: A row=lane&15, k=(lane>>4)*8+j; C/D col=lane&15, row=(lane>>4)*4+reg.
// ---------------------------------------------------------------------------
template<int POOL, int C1>
__global__ __launch_bounds__(256) void conv_mfma(
    const __bf16* __restrict__ inH, const __bf16* __restrict__ inL, long inZstride,
    const __bf16* __restrict__ wtH, const __bf16* __restrict__ wtL,
    float* __restrict__ out, long outZstride, float2* __restrict__ part,
    int HinP, int WinP, int Hout, int Wout, int Cout, int M, int niter,
    int H2, int W2, int H2c, int W2c)
{
    __shared__ __align__(16) char smem[30720];
    __bf16* AsH = (__bf16*)smem;              // [128][40] bf16
    __bf16* AsL = (__bf16*)(smem + 10240);
    __bf16* BsH = (__bf16*)(smem + 20480);    // [64][40]
    __bf16* BsL = (__bf16*)(smem + 25600);
    float2* red = (float2*)smem;              // [64][17] reuse after K loop

    // ---- bijective XCD swizzle (m204): round-robin orig -> chunked data id ----
    int bx;
    {
        int n = gridDim.x, orig = blockIdx.x;
        int q = n >> 3, r = n & 7;
        int xcd = orig & 7, idx = orig >> 3;
        bx = (xcd < r ? xcd * (q + 1) : r * (q + 1) + (xcd - r) * q) + idx;
    }

    const int tid   = threadIdx.x;
    const int mload = tid & 63;
    const int wv    = tid >> 6;
    const int ln15  = tid & 15;
    const int lhi   = (tid >> 4) & 3;

    const __bf16* ipH = inH + (size_t)blockIdx.z * inZstride;
    const __bf16* ipL = inL + (size_t)blockIdx.z * inZstride;

    auto geom = [&](int mA, size_t& base, bool& valid) {
        int nb, h, w;
        if (POOL) {
            int r = mA & 3, quad = mA >> 2;
            int cpi = H2c * W2c;
            nb = quad / cpi;
            int rem = quad - nb * cpi;
            int h2 = rem / W2c, w2 = rem - h2 * W2c;
            h = h2 * 2 + (r >> 1); w = w2 * 2 + (r & 1);
            valid = (mA < M) && (h < Hout) && (w < Wout);
        } else {
            int HW = Hout * Wout;
            valid = mA < M;
            int mm = valid ? mA : 0;
            nb = mm / HW;
            int rem = mm - nb * HW;
            h = rem / Wout; w = rem - h * Wout;
        }
        if (!valid) { nb = 0; h = 0; w = 0; }
        if (C1) base = ((size_t)(nb * 256 + h) * 256 + w) * 4;
        else    base = ((size_t)(nb * HinP + h) * WinP + w) * 64;
    };

    size_t base0, base1; bool mv0, mv1;
    geom(bx * 128 + mload, base0, mv0);
    geom(bx * 128 + 64 + mload, base1, mv1);

    const __bf16* wpH = wtH + (size_t)blockIdx.z * niter * 2048;
    const __bf16* wpL = wtL + (size_t)blockIdx.z * niter * 2048;

    f32x4 acc[2][4] = {};
    bf16x8 arH0, arL0, arH1, arL1, brH, brL, zero8;
#pragma unroll
    for (int j = 0; j < 8; ++j) zero8[j] = (__bf16)0.0f;

    auto loadA = [&](int it) {
        int k0 = it * 32 + wv * 8;
        int off;
        if (C1) { off = (k0 >> 5) * 1024 + (k0 & 31); }
        else { int tap = k0 >> 6; int kh = tap / 3; int kw = tap - 3 * kh;
               off = (kh * WinP + kw) * 64 + (k0 & 63); }
        arH0 = *(const bf16x8*)(ipH + base0 + off);
        arL0 = *(const bf16x8*)(ipL + base0 + off);
        arH1 = *(const bf16x8*)(ipH + base1 + off);
        arL1 = *(const bf16x8*)(ipL + base1 + off);
        if (!mv0) { arH0 = zero8; arL0 = zero8; }
        if (!mv1) { arH1 = zero8; arL1 = zero8; }
    };
    auto loadB = [&](int it) {
        size_t idx = (size_t)((it * 4 + wv) * 64 + mload) * 8;
        brH = *(const bf16x8*)(wpH + idx);
        brL = *(const bf16x8*)(wpL + idx);
    };

    loadA(0); loadB(0);
    for (int it = 0; it < niter; ++it) {
        __syncthreads();
        *(bf16x8*)&AsH[mload * 40 + wv * 8] = arH0;
        *(bf16x8*)&AsL[mload * 40 + wv * 8] = arL0;
        *(bf16x8*)&AsH[(64 + mload) * 40 + wv * 8] = arH1;
        *(bf16x8*)&AsL[(64 + mload) * 40 + wv * 8] = arL1;
        *(bf16x8*)&BsH[mload * 40 + wv * 8] = brH;
        *(bf16x8*)&BsL[mload * 40 + wv * 8] = brL;
        __syncthreads();
        if (it + 1 < niter) { loadA(it + 1); loadB(it + 1); }

        bf16x8 afH[2], afL[2];
#pragma unroll
        for (int q = 0; q < 2; ++q) {
            afH[q] = *(const bf16x8*)&AsH[(wv * 32 + q * 16 + ln15) * 40 + lhi * 8];
            afL[q] = *(const bf16x8*)&AsL[(wv * 32 + q * 16 + ln15) * 40 + lhi * 8];
        }
#pragma unroll
        for (int t = 0; t < 4; ++t) {
            bf16x8 bH = *(const bf16x8*)&BsH[(t * 16 + ln15) * 40 + lhi * 8];
            bf16x8 bL = *(const bf16x8*)&BsL[(t * 16 + ln15) * 40 + lhi * 8];
#pragma unroll
            for (int q = 0; q < 2; ++q) {
                acc[q][t] = __builtin_amdgcn_mfma_f32_16x16x32_bf16(afH[q], bH, acc[q][t], 0, 0, 0);
                acc[q][t] = __builtin_amdgcn_mfma_f32_16x16x32_bf16(afL[q], bH, acc[q][t], 0, 0, 0);
                acc[q][t] = __builtin_amdgcn_mfma_f32_16x16x32_bf16(afH[q], bL, acc[q][t], 0, 0, 0);
            }
        }
    }

    // ---- per-block per-channel (sum,sumsq) partials ----
    __syncthreads();
#pragma unroll
    for (int t = 0; t < 4; ++t) {
        float s = 0.f, s2 = 0.f;
#pragma unroll
        for (int q = 0; q < 2; ++q)
#pragma unroll
            for (int r = 0; r < 4; ++r) { float v = acc[q][t][r]; s += v; s2 += v * v; }
        red[(ln15 + 16 * t) * 17 + (wv * 4 + lhi)] = make_float2(s, s2);
    }
    __syncthreads();
    if (tid < 64) {
        float s = 0.f, s2 = 0.f;
#pragma unroll
        for (int q = 0; q < 16; ++q) { float2 v = red[tid * 17 + q]; s += v.x; s2 += v.y; }
        part[((size_t)blockIdx.z * 64 + tid) * gridDim.x + bx] = make_float2(s, s2);
    }

    // ---- NHWC output ----
    float* zout = out + (size_t)blockIdx.z * outZstride;
#pragma unroll
    for (int q = 0; q < 2; ++q) {
        const int mbase = bx * 128 + wv * 32 + q * 16 + lhi * 4;
        if (POOL) {
            if (mbase < M) {
                int quad = mbase >> 2;
                int cpi  = H2c * W2c;
                int nb2  = quad / cpi;
                int rem  = quad - nb2 * cpi;
                int h2 = rem / W2c, w2 = rem - h2 * W2c;
                if (h2 < H2 && w2 < W2) {
                    float* op = zout + ((size_t)(nb2 * H2 + h2) * W2 + w2) * Cout;
#pragma unroll
                    for (int t = 0; t < 4; ++t) {
                        int n = ln15 + 16 * t;
                        if (n < Cout) {
                            float mx = fmaxf(fmaxf(acc[q][t][0], acc[q][t][1]),
                                             fmaxf(acc[q][t][2], acc[q][t][3]));
                            op[n] = mx;
                        }
                    }
                }
            }
        } else {
#pragma unroll
            for (int r = 0; r < 4; ++r) {
                int m = mbase + r;
                if (m < M) {
                    float* op = zout + (size_t)m * Cout;
#pragma unroll
                    for (int t = 0; t < 4; ++t) {
                        int n = ln15 + 16 * t;
                        if (n < Cout) op[n] = acc[q][t][r];
                    }
                }
            }
        }
    }
}

// partials -> (mean, rsqrt(var+eps)) per (z,channel)
__global__ __launch_bounds__(256) void bn_finalize(const float2* __restrict__ part,
                                                   int nblkx, double Ninv,
                                                   float2* __restrict__ stats)
{
    __shared__ double sh[512];
    const int zc = blockIdx.x, tid = threadIdx.x;
    const float2* p = part + (size_t)zc * nblkx;
    double s = 0, s2 = 0;
    for (int i = tid; i < nblkx; i += 256) { s += p[i].x; s2 += p[i].y; }
    sh[tid] = s; sh[256 + tid] = s2;
    __syncthreads();
    for (int st = 128; st > 0; st >>= 1) {
        if (tid < st) { sh[tid] += sh[tid + st]; sh[256 + tid] += sh[256 + tid + st]; }
        __syncthreads();
    }
    if (tid == 0) {
        float mean = (float)(sh[0] * Ninv);
        float var  = (float)(sh[256] * Ninv - (double)mean * (double)mean);
        if (var < 0.f) var = 0.f;
        stats[zc] = make_float2(mean, rsqrtf(var + 1e-5f));
    }
}

// raw NHWC fp32 + stats -> padded NHWC bf16 hi/lo with zero border.
__global__ void bn_split(const float* __restrict__ raw, const float2* __restrict__ stats,
                         __bf16* __restrict__ outH, __bf16* __restrict__ outL,
                         int H, int W, int total)
{
    int idx = blockIdx.x * 256 + threadIdx.x;
    if (idx >= total) return;
    const int Hp = H + 2, Wp = W + 2;
    int c4 = idx & 15;
    int t  = idx >> 4;
    int wp = t % Wp; t /= Wp;
    int hp = t % Hp; int img = t / Hp;
    size_t o = (((size_t)img * Hp + hp) * Wp + wp) * 64 + c4 * 4;
    bf16x4 hi, lo;
    if (hp == 0 || hp == Hp - 1 || wp == 0 || wp == Wp - 1) {
#pragma unroll
        for (int j = 0; j < 4; ++j) { hi[j] = (__bf16)0.f; lo[j] = (__bf16)0.f; }
    } else {
        float4 v = *(const float4*)(raw + (((size_t)img * H + (hp - 1)) * W + (wp - 1)) * 64 + c4 * 4);
        const float2* st = stats + (img >> 4) * 64 + c4 * 4;
        float vv[4] = {v.x, v.y, v.z, v.w};
#pragma unroll
        for (int j = 0; j < 4; ++j) {
            float2 s = st[j];
            float r = fmaxf((vv[j] - s.x) * s.y, 0.f);
            __bf16 hh = (__bf16)r;
            hi[j] = hh; lo[j] = (__bf16)(r - (float)hh);
        }
    }
    *(bf16x4*)(outH + o) = hi;
    *(bf16x4*)(outL + o) = lo;
}

// pooled NHWC [P][16][H][W][64] + stats + d -> XB padded hi/lo [C][16][Hp][Wp][64]
__global__ void mix_split(const float* __restrict__ pooled, const float2* __restrict__ stats,
                          const float* __restrict__ d,
                          __bf16* __restrict__ outH, __bf16* __restrict__ outL,
                          int H, int W, int P, long strideP, int total)
{
    int idx = blockIdx.x * 256 + threadIdx.x;
    if (idx >= total) return;
    const int Hp = H + 2, Wp = W + 2;
    int c4 = idx & 15;
    int t  = idx >> 4;
    int wp = t % Wp; t /= Wp;
    int hp = t % Hp; t /= Hp;
    int n  = t & 15;
    int cc = t >> 4;
    size_t o = (((size_t)(cc * 16 + n) * Hp + hp) * Wp + wp) * 64 + c4 * 4;
    bf16x4 hi, lo;
    if (hp == 0 || hp == Hp - 1 || wp == 0 || wp == Wp - 1) {
#pragma unroll
        for (int j = 0; j < 4; ++j) { hi[j] = (__bf16)0.f; lo[j] = (__bf16)0.f; }
    } else {
        float a[4] = {0.f, 0.f, 0.f, 0.f};
        const float* pb = pooled + (((size_t)n * H + (hp - 1)) * W + (wp - 1)) * 64 + c4 * 4;
        for (int p = 0; p < P; ++p) {
            float4 v = *(const float4*)(pb + (size_t)p * strideP);
            const float2* st = stats + p * 64 + c4 * 4;
            float dc = d[cc * P + p];
            float vv[4] = {v.x, v.y, v.z, v.w};
#pragma unroll
            for (int j = 0; j < 4; ++j) {
                float2 s = st[j];
                a[j] = fmaf(dc, fmaxf((vv[j] - s.x) * s.y, 0.f), a[j]);
            }
        }
#pragma unroll
        for (int j = 0; j < 4; ++j) {
            __bf16 hh = (__bf16)a[j];
            hi[j] = hh; lo[j] = (__bf16)(a[j] - (float)hh);
        }
    }
    *(bf16x4*)(outH + o) = hi;
    *(bf16x4*)(outL + o) = lo;
}

// L3 mix: pooled [16][16][7][7][32] -> XB3 fp32 [40][16][7][7][32]
__global__ void mix_last(const float* __restrict__ pooled, const float2* __restrict__ stats,
                         const float* __restrict__ d, float* __restrict__ out, int total)
{
    int idx = blockIdx.x * 256 + threadIdx.x;
    if (idx >= total) return;
    int c  = idx & 31;
    int t  = idx >> 5;
    int hw = t % 49; t /= 49;
    int n  = t & 15;
    int a  = t >> 4;
    float acc = 0.f;
    const float* pb = pooled + ((size_t)n * 49 + hw) * 32 + c;
    for (int p = 0; p < 16; ++p) {
        float2 s = stats[p * 64 + c];
        acc = fmaf(d[a * 16 + p], fmaxf((pb[(size_t)p * 25088] - s.x) * s.y, 0.f), acc);
    }
    out[idx] = acc;
}

// x NCHW [16][3][256][256] -> packed NHWC4 hi/lo [16][256][256][4]
__global__ void prep_x(const float* __restrict__ x, __bf16* __restrict__ xH,
                       __bf16* __restrict__ xL)
{
    int idx = blockIdx.x * 256 + threadIdx.x;   // 16*65536
    if (idx >= 16 * 65536) return;
    int n = idx >> 16, hw = idx & 65535;
    bf16x4 hi, lo;
#pragma unroll
    for (int ci = 0; ci < 3; ++ci) {
        float v = x[((size_t)n * 3 + ci) * 65536 + hw];
        __bf16 hh = (__bf16)v;
        hi[ci] = hh; lo[ci] = (__bf16)(v - (float)hh);
    }
    hi[3] = (__bf16)0.f; lo[3] = (__bf16)0.f;
    *(bf16x4*)(xH + (size_t)idx * 4) = hi;
    *(bf16x4*)(xL + (size_t)idx * 4) = lo;
}

// conv1 weights [64][3][7][7] -> hi/lo panels [28 kblk][64][8], k=kh*32+kw*4+ci
__global__ void wtrans1(const float* __restrict__ w, __bf16* __restrict__ wH,
                        __bf16* __restrict__ wL)
{
    int i = blockIdx.x * 256 + threadIdx.x;
    if (i >= 28 * 512) return;
    int j = i & 7, n = (i >> 3) & 63, kb = i >> 9;
    int k = kb * 8 + j;
    int kh = k >> 5, r = k & 31, kw = r >> 2, ci = r & 3;
    float v = (kw < 7 && ci < 3) ? w[((n * 3 + ci) * 7 + kh) * 7 + kw] : 0.f;
    __bf16 hh = (__bf16)v;
    wH[i] = hh; wL[i] = (__bf16)(v - (float)hh);
}

// 3x3 weights [P][Cout][64][3][3] -> hi/lo panels [p][72 kblk][64][8],
// k = (kh*3+kw)*64 + ci
__global__ void wtrans3(const float* __restrict__ w, __bf16* __restrict__ wH,
                        __bf16* __restrict__ wL, int P, int Cout)
{
    int total = P * 72 * 512;
    for (int i = blockIdx.x * 256 + threadIdx.x; i < total; i += gridDim.x * 256) {
        int j = i & 7, n = (i >> 3) & 63, kb = (i >> 9) % 72, p = (i >> 9) / 72;
        int k = kb * 8 + j;
        int ci = k & 63, tap = k >> 6, kh = tap / 3, kw = tap - 3 * kh;
        float v = (n < Cout) ? w[(((size_t)(p * Cout + n)) * 64 + ci) * 9 + kh * 3 + kw] : 0.f;
        __bf16 hh = (__bf16)v;
        wH[i] = hh; wL[i] = (__bf16)(v - (float)hh);
    }
}

// d = softmax_p( log(softmax_p(br*2)) / t ) for all 4 layers
__global__ void dcalc(const float* __restrict__ br0, const float* __restrict__ br1,
                      const float* __restrict__ br2, const float* __restrict__ br3,
                      const void* __restrict__ tptr, float* __restrict__ D)
{
    const int L = blockIdx.x;
    const float* br; int C, P, off;
    if      (L == 0) { br = br0; C = 4;  P = 2;  off = 0;   }
    else if (L == 1) { br = br1; C = 8;  P = 4;  off = 8;   }
    else if (L == 2) { br = br2; C = 16; P = 8;  off = 40;  }
    else             { br = br3; C = 40; P = 16; off = 168; }
    int ti = *(const int*)tptr;
    float t = (ti > 0 && ti < 1000000) ? (float)ti : *(const float*)tptr;
    const int c = threadIdx.x;
    if (c >= C) return;
    float u[16];
    float mx = -1e30f;
#pragma unroll
    for (int p = 0; p < 16; ++p) if (p < P) { u[p] = br[c * P + p] * 2.0f; mx = fmaxf(mx, u[p]); }
    float se = 0.f;
#pragma unroll
    for (int p = 0; p < 16; ++p) if (p < P) se += expf(u[p] - mx);
    float lse = mx + logf(se);
    float mx2 = -1e30f;
#pragma unroll
    for (int p = 0; p < 16; ++p) if (p < P) { u[p] = (u[p] - lse) / t; mx2 = fmaxf(mx2, u[p]); }
    float se2 = 0.f;
#pragma unroll
    for (int p = 0; p < 16; ++p) if (p < P) { u[p] = expf(u[p] - mx2); se2 += u[p]; }
#pragma unroll
    for (int p = 0; p < 16; ++p) if (p < P) D[off + c * P + p] = u[p] / se2;
}

// h1[a,b,i] = relu( sum_f f[a,b,f]*fw1[a,f,i] + fb1[a,i] ); f stored (h,w,c),
// fw1 indexed (c,h,w)
__global__ __launch_bounds__(128) void fc1_k(const float* __restrict__ f,
                                             const float* __restrict__ w1,
                                             const float* __restrict__ b1,
                                             float* __restrict__ h1)
{
    const int a = blockIdx.x >> 4;
    const int b = blockIdx.x & 15;
    const int i = threadIdx.x;
    const float* fv = f + ((size_t)a * 16 + b) * 1568;
    const float* wv = w1 + (size_t)a * 1568 * 128 + i;
    float acc = b1[a * 128 + i];
    for (int hw = 0; hw < 49; ++hw)
        for (int c = 0; c < 32; ++c)
            acc = fmaf(fv[hw * 32 + c], wv[(size_t)(c * 49 + hw) * 128], acc);
    h1[((size_t)a * 16 + b) * 128 + i] = fmaxf(acc, 0.f);
}

__global__ __launch_bounds__(128) void fc23_k(const float* __restrict__ h1,
                                              const float* __restrict__ w2,
                                              const float* __restrict__ b2,
                                              const float* __restrict__ w3,
                                              const float* __restrict__ b3,
                                              float* __restrict__ out)
{
    __shared__ float sh1[16][128];
    __shared__ float sh2[16][128];
    const int a = blockIdx.x;
    const int i = threadIdx.x;
    for (int b = 0; b < 16; ++b) sh1[b][i] = h1[((size_t)a * 16 + b) * 128 + i];
    __syncthreads();
    float acc[16];
#pragma unroll
    for (int b = 0; b < 16; ++b) acc[b] = b2[a * 128 + i];
    for (int ff = 0; ff < 128; ++ff) {
        float wv = w2[((size_t)a * 128 + ff) * 128 + i];
#pragma unroll
        for (int b = 0; b < 16; ++b) acc[b] = fmaf(sh1[b][ff], wv, acc[b]);
    }
    for (int b = 0; b < 16; ++b) sh2[b][i] = fmaxf(acc[b], 0.f);
    __syncthreads();
    if (i < 16) {
        float o = b3[a];
        for (int ff = 0; ff < 128; ++ff) o = fmaf(sh2[i][ff], w3[a * 128 + ff], o);
        out[i * 40 + a] = o;
    }
}

extern "C" void kernel_launch(void* const* d_in, const int* in_sizes, int n_in,
                              void* d_out, int out_size, void* d_ws, size_t ws_size,
                              hipStream_t stream)
{
    (void)in_sizes; (void)n_in;

    const float* x   = (const float*)d_in[0];
    const float* w10 = (const float*)d_in[1];
    const float* wa[4] = {(const float*)d_in[3],  (const float*)d_in[7],
                          (const float*)d_in[11], (const float*)d_in[15]};
    const float* wb[4] = {(const float*)d_in[5],  (const float*)d_in[9],
                          (const float*)d_in[13], (const float*)d_in[17]};
    const float* br[4] = {(const float*)d_in[19], (const float*)d_in[20],
                          (const float*)d_in[21], (const float*)d_in[22]};
    const float* fw1 = (const float*)d_in[23];
    const float* fb1 = (const float*)d_in[24];
    const float* fw2 = (const float*)d_in[25];
    const float* fb2 = (const float*)d_in[26];
    const float* fw3 = (const float*)d_in[27];
    const float* fb3 = (const float*)d_in[28];
    float* out = (float*)d_out;

    const int Pl[4]  = {2, 4, 8, 16};
    const int CBs[4] = {64, 64, 64, 32};

    // ---- workspace arenas (f32 units); total 60,264,704 f32 = 241.06 MB ----
    const size_t NEED = 60264704ull * 4ull;
    if (ws_size < NEED) {
        hipMemsetAsync(d_out, 0, (size_t)out_size * sizeof(float), stream);
        return;
    }
    float* ws = (float*)d_ws;
    size_t o = 0;
    __bf16* WT1H = (__bf16*)(ws + o); o += 7168;   // 14336 bf16
    __bf16* WT1L = (__bf16*)(ws + o); o += 7168;
    __bf16 *WTAH[4], *WTAL[4], *WTBH[4], *WTBL[4];
    for (int L = 0; L < 4; ++L) {                  // P*72*512 bf16 each
        WTAH[L] = (__bf16*)(ws + o); o += (size_t)Pl[L] * 18432;
        WTAL[L] = (__bf16*)(ws + o); o += (size_t)Pl[L] * 18432;
        WTBH[L] = (__bf16*)(ws + o); o += (size_t)Pl[L] * 18432;
        WTBL[L] = (__bf16*)(ws + o); o += (size_t)Pl[L] * 18432;
    }
    float*  D     = ws + o; o += 1024;
    float2* STATS = (float2*)(ws + o); o += 4352;
    float2* STATS_C1 = STATS;
    float2* STATS_A  = STATS + 64;
    float2* STATS_B  = STATS + 1088;
    float*  H1 = ws + o; o += 81920;
    float*  A6 = ws + o; o += 524288;      // small conv partials
    float*  A5 = ws + o; o += 7872512;     // pooled raw / conv1 partials
    float*  A4 = ws + o; o += 16000000;    // raw conv outputs (fp32 NHWC)
    float*  A3 = ws + o; o += 16777216;    // split bufs (hi/lo bf16) / xc
    float*  A2 = ws + o; o += 16777216;    // Y / XB chain

    float2* PART   = (float2*)A6;
    float2* PARTC1 = (float2*)A5;
    __bf16* xcH = (__bf16*)A3;
    __bf16* xcL = (__bf16*)(A3 + 2097152);
    __bf16* A2H = (__bf16*)A2;             // hi at A2[0:], lo after
    __bf16* A2L = (__bf16*)(A2 + 8388608);
    __bf16* A3H = (__bf16*)A3;
    __bf16* A3L = (__bf16*)(A3 + 8388608);

    // ---- weights + mix coefficients + conv1 input prep ----
    prep_x<<<4096, 256, 0, stream>>>(x, xcH, xcL);
    wtrans1<<<56, 256, 0, stream>>>(w10, WT1H, WT1L);
    for (int L = 0; L < 4; ++L) {
        int tA = Pl[L] * 72 * 512;
        wtrans3<<<DIVUP(tA, 256), 256, 0, stream>>>(wa[L], WTAH[L], WTAL[L], Pl[L], 64);
        wtrans3<<<DIVUP(tA, 256), 256, 0, stream>>>(wb[L], WTBH[L], WTBL[L], Pl[L], CBs[L]);
    }
    dcalc<<<4, 64, 0, stream>>>(br[0], br[1], br[2], br[3], d_in[29], D);

    // ---- conv1: xc -> pooled raw A4 [16,125,125,64] + stats ----
    conv_mfma<1, 1><<<dim3(7813, 1, 1), 256, 0, stream>>>(
        xcH, xcL, 0, WT1H, WT1L, A4, 0, PARTC1,
        256, 256, 250, 250, 64, 1000000, 7, 125, 125, 125, 125);
    bn_finalize<<<64, 256, 0, stream>>>(PARTC1, 7813, 1.0 / 1000000.0, STATS_C1);
    // Y = bn_split(A4) -> A2 padded [16][127][127][64]
    bn_split<<<DIVUP(16 * 127 * 127 * 16, 256), 256, 0, stream>>>(
        A4, STATS_C1, A2H, A2L, 125, 125, 16 * 127 * 127 * 16);

    // ---- layer 0 (per parent; Y shared) ----
    for (int p = 0; p < 2; ++p) {
        conv_mfma<0, 0><<<dim3(1954, 1, 1), 256, 0, stream>>>(
            A2H, A2L, 0, WTAH[0] + (size_t)p * 36864, WTAL[0] + (size_t)p * 36864,
            A4, 0, PART, 127, 127, 125, 125, 64, 250000, 18, 0, 0, 1, 1);
        bn_finalize<<<64, 256, 0, stream>>>(PART, 1954, 1.0 / 250000.0, STATS_A);
        bn_split<<<DIVUP(16 * 127 * 127 * 16, 256), 256, 0, stream>>>(
            A4, STATS_A, A3H, A3L, 125, 125, 16 * 127 * 127 * 16);
        conv_mfma<1, 0><<<dim3(1985, 1, 1), 256, 0, stream>>>(
            A3H, A3L, 0, WTBH[0] + (size_t)p * 36864, WTBL[0] + (size_t)p * 36864,
            A5 + (size_t)p * 3936256, 0, PART,
            127, 127, 125, 125, 64, 254016, 18, 62, 62, 63, 63);
        bn_finalize<<<64, 256, 0, stream>>>(PART, 1985, 1.0 / 250000.0, STATS_B + p * 64);
    }
    mix_split<<<DIVUP(4 * 16 * 64 * 64 * 16, 256), 256, 0, stream>>>(
        A5, STATS_B, D + 0, A2H, A2L, 62, 62, 2, 3936256, 4 * 16 * 64 * 64 * 16);

    // ---- layer 1 (z=4) ----
    conv_mfma<0, 0><<<dim3(481, 1, 4), 256, 0, stream>>>(
        A2H, A2L, 4194304, WTAH[1], WTAL[1], A4, 3936256, PART,
        64, 64, 62, 62, 64, 61504, 18, 0, 0, 1, 1);
    bn_finalize<<<256, 256, 0, stream>>>(PART, 481, 1.0 / 61504.0, STATS_A);
    bn_split<<<DIVUP(64 * 64 * 64 * 16, 256), 256, 0, stream>>>(
        A4, STATS_A, A3H, A3L, 62, 62, 64 * 64 * 64 * 16);
    conv_mfma<1, 0><<<dim3(481, 1, 4), 256, 0, stream>>>(
        A3H, A3L, 4194304, WTBH[1], WTBL[1], A5, 984064, PART,
        64, 64, 62, 62, 64, 61504, 18, 31, 31, 31, 31);
    bn_finalize<<<256, 256, 0, stream>>>(PART, 481, 1.0 / 61504.0, STATS_B);
    mix_split<<<DIVUP(8 * 16 * 33 * 33 * 16, 256), 256, 0, stream>>>(
        A5, STATS_B, D + 8, A2H, A2L, 31, 31, 4, 984064, 8 * 16 * 33 * 33 * 16);

    // ---- layer 2 (z=8) ----
    conv_mfma<0, 0><<<dim3(121, 1, 8), 256, 0, stream>>>(
        A2H, A2L, 1115136, WTAH[2], WTAL[2], A4, 984064, PART,
        33, 33, 31, 31, 64, 15376, 18, 0, 0, 1, 1);
    bn_finalize<<<512, 256, 0, stream>>>(PART, 121, 1.0 / 15376.0, STATS_A);
    bn_split<<<DIVUP(128 * 33 * 33 * 16, 256), 256, 0, stream>>>(
        A4, STATS_A, A3H, A3L, 31, 31, 128 * 33 * 33 * 16);
    conv_mfma<1, 0><<<dim3(128, 1, 8), 256, 0, stream>>>(
        A3H, A3L, 1115136, WTBH[2], WTBL[2], A5, 230400, PART,
        33, 33, 31, 31, 64, 16384, 18, 15, 15, 16, 16);
    bn_finalize<<<512, 256, 0, stream>>>(PART, 128, 1.0 / 15376.0, STATS_B);
    mix_split<<<DIVUP(16 * 16 * 17 * 17 * 16, 256), 256, 0, stream>>>(
        A5, STATS_B, D + 40, A2H, A2L, 15, 15, 8, 230400, 16 * 16 * 17 * 17 * 16);

    // ---- layer 3 (z=16) ----
    conv_mfma<0, 0><<<dim3(29, 1, 16), 256, 0, stream>>>(
        A2H, A2L, 295936, WTAH[3], WTAL[3], A4, 230400, PART,
        17, 17, 15, 15, 64, 3600, 18, 0, 0, 1, 1);
    bn_finalize<<<1024, 256, 0, stream>>>(PART, 29, 1.0 / 3600.0, STATS_A);
    bn_split<<<DIVUP(256 * 17 * 17 * 16, 256), 256, 0, stream>>>(
        A4, STATS_A, A3H, A3L, 15, 15, 256 * 17 * 17 * 16);
    conv_mfma<1, 0><<<dim3(32, 1, 16), 256, 0, stream>>>(
        A3H, A3L, 295936, WTBH[3], WTBL[3], A5, 25088, PART,
        17, 17, 15, 15, 32, 4096, 18, 7, 7, 8, 8);
    bn_finalize<<<1024, 256, 0, stream>>>(PART, 32, 1.0 / 3600.0, STATS_B);
    mix_last<<<DIVUP(40 * 16 * 49 * 32, 256), 256, 0, stream>>>(
        A5, STATS_B, D + 168, A2, 40 * 16 * 49 * 32);

    // ---- FC heads ----
    fc1_k<<<640, 128, 0, stream>>>(A2, fw1, fb1, H1);
    fc23_k<<<40, 128, 0, stream>>>(H1, fw2, fb2, fw3, fb3, out);
}